// Round 8
// baseline (920.360 us; speedup 1.0000x reference)
//
#include <hip/hip_runtime.h>
#include <math.h>
#include <limits.h>

#define DF 512
#define DH 64
#define DL 16
#define NC 10
#define NF 10
#define KPROP 10

#define BSH 7                  // bucket shift: 128 nodes per bucket
#define BW  (1 << BSH)
#define MAXB 1024
#define TILE 16384

__device__ __forceinline__ float softplus_(float x){
  return fmaxf(x, 0.0f) + log1pf(expf(-fabsf(x)));
}

// -------- GEMM1 fused with z-projection: z = relu(x@W1+b1) @ W2 + b2 --------
// (round-6 proven config: 64x64 tile, 4x4 microtile, BK=32, 124us)
#define BM 64
#define BN 64
#define BK 32
__global__ __launch_bounds__(256) void k_gemm1z(const float* __restrict__ x,
    const float* __restrict__ W1, const float* __restrict__ b1,
    const float* __restrict__ W2, const float* __restrict__ b2,
    float* __restrict__ z, int N)
{
  __shared__ float smem[2*BK*(BM+4)];           // At | Bs, later overlaid by hs[64][68]
  float (*At)[BM+4] = (float(*)[BM+4])smem;
  float (*Bs)[BN+4] = (float(*)[BN+4])(smem + BK*(BM+4));
  __shared__ float W2s[DH][DL];
  __shared__ float b2s[DL];
  const int tid = threadIdx.x;
  for (int i = tid; i < DH*DL; i += 256) W2s[i>>4][i&15] = W2[i];
  if (tid < DL) b2s[tid] = b2[tid];
  const int tx = tid & 15, ty = tid >> 4;
  const int row0 = blockIdx.x * BM;
  float acc[4][4] = {};
  for (int k0 = 0; k0 < DF; k0 += BK) {
    #pragma unroll
    for (int i = 0; i < 2; ++i) {
      int idx = tid + i*256;
      int r  = idx >> 3;
      int kk = (idx & 7) << 2;
      int row = row0 + r;
      float4 va = make_float4(0.f,0.f,0.f,0.f);
      if (row < N) va = *(const float4*)&x[(size_t)row*DF + k0 + kk];
      At[kk+0][r]=va.x; At[kk+1][r]=va.y; At[kk+2][r]=va.z; At[kk+3][r]=va.w;
      int r2 = idx >> 4;
      int c4 = (idx & 15) << 2;
      float4 vb = *(const float4*)&W1[(size_t)(k0+r2)*DH + c4];
      Bs[r2][c4+0]=vb.x; Bs[r2][c4+1]=vb.y; Bs[r2][c4+2]=vb.z; Bs[r2][c4+3]=vb.w;
    }
    __syncthreads();
    #pragma unroll
    for (int kk = 0; kk < BK; ++kk) {
      float4 av = *(const float4*)&At[kk][ty<<2];
      float4 bv = *(const float4*)&Bs[kk][tx<<2];
      float a4[4]={av.x,av.y,av.z,av.w};
      float b4[4]={bv.x,bv.y,bv.z,bv.w};
      #pragma unroll
      for (int i=0;i<4;++i)
        #pragma unroll
        for (int j=0;j<4;++j) acc[i][j] = fmaf(a4[i], b4[j], acc[i][j]);
    }
    __syncthreads();
  }
  // epilogue: h tile -> LDS (overlay), then z = h@W2+b2
  float4 bias = ((const float4*)b1)[tx];
  float bias4[4] = {bias.x, bias.y, bias.z, bias.w};
  float (*hs)[BM+4] = (float(*)[BM+4])smem;
  #pragma unroll
  for (int i=0;i<4;++i){
    #pragma unroll
    for (int j=0;j<4;++j)
      hs[(ty<<2)+i][(tx<<2)+j] = fmaxf(acc[i][j] + bias4[j], 0.0f);
  }
  __syncthreads();
  int row = tid >> 2, lg = tid & 3;
  float4 zacc = ((const float4*)b2s)[lg];
  #pragma unroll 8
  for (int k = 0; k < DH; ++k){
    float hv = hs[row][k];
    float4 wv = *(const float4*)&W2s[k][lg<<2];
    zacc.x = fmaf(hv, wv.x, zacc.x);
    zacc.y = fmaf(hv, wv.y, zacc.y);
    zacc.z = fmaf(hv, wv.z, zacc.z);
    zacc.w = fmaf(hv, wv.w, zacc.w);
  }
  int grow = row0 + row;
  if (grow < N) ((float4*)z)[(size_t)grow*4 + lg] = zacc;
}

// -------- radial flows: one thread per (node, class) --------
// emits x0[N][16]; c/y split into lo (classes 0-7) and hi (8-15) halves:
// c = dinv*x0, y = 0.1*dinv*x0.
__global__ __launch_bounds__(256) void k_flow2(const float* __restrict__ z,
    const float* __restrict__ pc, const float* __restrict__ z0g,
    const float* __restrict__ apg, const float* __restrict__ fbg,
    const float* __restrict__ dinv,
    float* __restrict__ x0, float* __restrict__ cL, float* __restrict__ cH,
    float* __restrict__ yL, float* __restrict__ yH, int N)
{
  __shared__ float z0s[NF][NC][DL];
  __shared__ float alps[NF][NC];
  __shared__ float bhs[NF][NC];
  __shared__ float lpc[NC];
  int tid = threadIdx.x;
  for (int i = tid; i < NF*NC*DL; i += 256)
    z0s[(i>>4)/NC][(i>>4)%NC][i&15] = z0g[i];
  if (tid < NF*NC){
    int l = tid/NC, c = tid%NC;
    float al = softplus_(apg[tid]);
    alps[l][c] = al;
    bhs[l][c]  = -al + softplus_(fbg[tid]);
  }
  if (tid < NC) lpc[tid] = __logf(pc[tid]);
  __syncthreads();

  int idx = blockIdx.x*256 + tid;
  int n = idx >> 4, c = idx & 15;
  if (n >= N) return;
  float dn = dinv[n];
  if (c >= NC){
    x0[idx] = 0.f;
    cH[(size_t)n*8 + (c-8)] = 0.f;
    yH[(size_t)n*8 + (c-8)] = 0.f;
    return;
  }

  float zz[DL];
  const float4* z4 = (const float4*)z;
  #pragma unroll
  for (int q=0; q<4; ++q){
    float4 v = z4[(size_t)n*4 + q];
    zz[q*4+0]=v.x; zz[q*4+1]=v.y; zz[q*4+2]=v.z; zz[q*4+3]=v.w;
  }
  const float NEGHALFD_LOG2PI = -14.703016531274762f;  // -8*log(2*pi)
  const float LOGSCALE        =  20.248193975754326f;  //  8*log(4*pi)
  float sld = 0.f;
  #pragma unroll 1
  for (int l=0; l<NF; ++l){
    float al = alps[l][c], bhat = bhs[l][c];
    float dz[DL]; float r2 = 0.f;
    #pragma unroll
    for (int d=0; d<DL; ++d){ float t = zz[d] - z0s[l][c][d]; dz[d]=t; r2 = fmaf(t,t,r2); }
    float r  = sqrtf(r2);
    float hh = 1.0f/(al + r);
    float bh = bhat*hh;
    #pragma unroll
    for (int d=0; d<DL; ++d) zz[d] = fmaf(bh, dz[d], zz[d]);
    sld += 15.0f*__logf(1.0f + bh) + __logf(1.0f + bh - bhat*r*hh*hh);
  }
  float q2 = 0.f;
  #pragma unroll
  for (int d=0; d<DL; ++d) q2 = fmaf(zz[d], zz[d], q2);
  float v = -0.5f*q2 + NEGHALFD_LOG2PI + sld + lpc[c] + LOGSCALE;
  v = fminf(fmaxf(v, -30.f), 30.f);
  float xv = __expf(v);
  x0[idx] = xv;
  float cv = dn*xv;
  if (c < 8){
    cL[(size_t)n*8 + c] = cv;
    yL[(size_t)n*8 + c] = 0.1f*cv;
  } else {
    cH[(size_t)n*8 + (c-8)] = cv;
    yH[(size_t)n*8 + (c-8)] = 0.1f*cv;
  }
}

// ---------------- bucketed CSR construction ----------------
__global__ __launch_bounds__(256) void k_bhist(const int* __restrict__ dst,
    int* __restrict__ bCnt, int E, int B)
{
  __shared__ int hh[MAXB];
  int tid = threadIdx.x;
  for (int b = tid; b < B; b += 256) hh[b] = 0;
  __syncthreads();
  for (int i = blockIdx.x*256 + tid; i < E; i += gridDim.x*256)
    atomicAdd(&hh[dst[i] >> BSH], 1);
  __syncthreads();
  for (int b = tid; b < B; b += 256) if (hh[b]) atomicAdd(&bCnt[b], hh[b]);
}

__global__ void k_bscan(const int* __restrict__ bCnt, int* __restrict__ bOff, int B){
  if (blockIdx.x==0 && threadIdx.x==0){
    int run = 0;
    for (int b=0;b<B;++b){ bOff[b]=run; run+=bCnt[b]; }
    bOff[B]=run;
  }
}

__global__ __launch_bounds__(256) void k_bscatter(const int* __restrict__ src,
    const int* __restrict__ dst, const int* __restrict__ bOff,
    int* __restrict__ bCur, int* __restrict__ bp, int E, int B)
{
  __shared__ int hc[MAXB];
  __shared__ int hb[MAXB];
  int tid = threadIdx.x;
  int base = blockIdx.x * TILE;
  int lim  = base + TILE; if (lim > E) lim = E;
  for (int b = tid; b < B; b += 256) hc[b] = 0;
  __syncthreads();
  for (int i = base + tid; i < lim; i += 256)
    atomicAdd(&hc[dst[i] >> BSH], 1);
  __syncthreads();
  for (int b = tid; b < B; b += 256){
    int c = hc[b];
    hb[b] = c ? atomicAdd(&bCur[b], c) : 0;
    hc[b] = 0;
  }
  __syncthreads();
  for (int i = base + tid; i < lim; i += 256){
    int d = dst[i];
    int b = d >> BSH;
    int pos = bOff[b] + hb[b] + atomicAdd(&hc[b], 1);
    bp[pos] = (src[i] << BSH) | (d & (BW-1));
  }
}

// per-bucket in-degree count (+1 self loop) fused with dinv/dinv2
__global__ __launch_bounds__(256) void k_bdeg(const int* __restrict__ bp,
    const int* __restrict__ bOff, int* __restrict__ deg,
    float* __restrict__ dinv, float* __restrict__ dinv2, int N)
{
  __shared__ int cur[BW];
  int tid = threadIdx.x;
  int b = blockIdx.x;
  if (tid < BW) cur[tid] = 0;
  __syncthreads();
  int s = bOff[b], e = bOff[b+1];
  for (int i = s + tid; i < e; i += 256)
    atomicAdd(&cur[bp[i] & (BW-1)], 1);
  __syncthreads();
  int node = (b << BSH) + tid;
  if (tid < BW && node < N){
    int d = cur[tid] + 1;                 // +1 self loop
    deg[node] = d;
    float dv = 1.0f / sqrtf((float)d);
    dinv[node]  = dv;
    dinv2[node] = dv*dv;
  }
}

__global__ __launch_bounds__(256) void k_scan_part(const int* __restrict__ deg,
    int* __restrict__ part, int N){
  __shared__ int sd[256];
  int base = blockIdx.x*1024;
  int tid = threadIdx.x;
  int s = 0;
  #pragma unroll
  for (int i=0;i<4;++i){ int idx = base + tid*4 + i; if (idx < N) s += deg[idx]; }
  sd[tid] = s; __syncthreads();
  for (int ofs=128; ofs>0; ofs>>=1){ if (tid<ofs) sd[tid]+=sd[tid+ofs]; __syncthreads(); }
  if (tid==0) part[blockIdx.x] = sd[0];
}

__global__ void k_scan_top(int* part, int nb){
  if (blockIdx.x==0 && threadIdx.x==0){
    int run = 0;
    for (int i=0;i<nb;++i){ int v = part[i]; part[i] = run; run += v; }
  }
}

__global__ __launch_bounds__(256) void k_scan_final(const int* __restrict__ deg,
    const int* __restrict__ part, int* __restrict__ off, int N, int E)
{
  __shared__ int sc[256];
  int base = blockIdx.x*1024;
  int tid = threadIdx.x;
  int v[4]; int s = 0;
  #pragma unroll
  for (int i=0;i<4;++i){ int idx = base + tid*4 + i; v[i] = (idx<N)?deg[idx]:0; s += v[i]; }
  sc[tid] = s; __syncthreads();
  for (int ofs=1; ofs<256; ofs<<=1){
    int t = (tid>=ofs) ? sc[tid-ofs] : 0;
    __syncthreads();
    sc[tid] += t;
    __syncthreads();
  }
  int ex = sc[tid] - s + part[blockIdx.x];
  #pragma unroll
  for (int i=0;i<4;++i){
    int idx = base + tid*4 + i;
    if (idx < N){
      off[idx] = ex;
      if (idx == N-1) off[N] = ex + v[i];
      ex += v[i];
    }
  }
}

// place self edge (slot 0) + src ints at CSR positions
__global__ __launch_bounds__(256) void k_place(const int* __restrict__ bp,
    const int* __restrict__ bOff, const int* __restrict__ off,
    int* __restrict__ csr, int N)
{
  __shared__ int cur[BW];
  int tid = threadIdx.x;
  int b = blockIdx.x;
  int node0 = b << BSH;
  if (tid < BW){
    cur[tid] = 1;                                 // slot 0 reserved for self
    int node = node0 + tid;
    if (node < N) csr[off[node]] = node;
  }
  __syncthreads();
  int s = bOff[b], e = bOff[b+1];
  for (int i = s + tid; i < e; i += 256){
    int v  = bp[i];
    int dl = v & (BW-1);
    int sn = v >> BSH;
    int d  = node0 + dl;
    int p  = off[d] + atomicAdd(&cur[dl], 1);
    csr[p] = sn;
  }
}

// ---- canonicalize segment order (stable value-rank via shuffles) ----
__global__ __launch_bounds__(256) void k_rank(int* __restrict__ csr,
    const int* __restrict__ off, int N)
{
  int wid  = (blockIdx.x*256 + threadIdx.x) >> 6;
  int lane = threadIdx.x & 63;
  if (wid >= N) return;
  int s = off[wid], e = off[wid+1];
  int d = e - s;
  if (d <= 1) return;
  if (d <= 64){
    int v = (lane < d) ? csr[s+lane] : INT_MAX;
    int rank = 0;
    for (int j = 0; j < d; ++j){
      int bv = __shfl(v, j);
      rank += (bv < v) || (bv == v && j < lane);
    }
    if (lane < d) csr[s+rank] = v;
  } else if (d <= 256){
    int v0 = (lane      < d) ? csr[s+lane      ] : INT_MAX;
    int v1 = (lane+64   < d) ? csr[s+lane+64   ] : INT_MAX;
    int v2 = (lane+128  < d) ? csr[s+lane+128  ] : INT_MAX;
    int v3 = (lane+192  < d) ? csr[s+lane+192  ] : INT_MAX;
    int r0=0,r1=0,r2=0,r3=0;
    for (int j = 0; j < d; ++j){
      int slot = j >> 6, jl = j & 63;
      int bv = (slot==0) ? __shfl(v0,jl) : (slot==1) ? __shfl(v1,jl)
             : (slot==2) ? __shfl(v2,jl) : __shfl(v3,jl);
      r0 += (bv < v0) || (bv == v0 && j < lane);
      r1 += (bv < v1) || (bv == v1 && j < lane+64);
      r2 += (bv < v2) || (bv == v2 && j < lane+128);
      r3 += (bv < v3) || (bv == v3 && j < lane+192);
    }
    if (lane      < d) csr[s+r0]=v0;
    if (lane+64   < d) csr[s+r1]=v1;
    if (lane+128  < d) csr[s+r2]=v2;
    if (lane+192  < d) csr[s+r3]=v3;
  } else {
    if (lane == 0){
      for (int i = s+1; i < e; ++i){
        int key = csr[i]; int j = i-1;
        while (j >= s && csr[j] > key){ csr[j+1] = csr[j]; --j; }
        csr[j+1] = key;
      }
    }
  }
}

// ---- APPNP c-space half-iteration, XCD-steered:
// XCDs 0-3 process the lo class-half (cL, 3.2MB, L2-resident),
// XCDs 4-7 the hi half. half = (blockIdx%8)>>2, node_blk = (bid>>3)*4+(bid&3).
// 2 threads per node per half; c' = 0.9*dinv2*sum(c[src]) + y.
__global__ __launch_bounds__(256) void k_prop_half(
    const float* __restrict__ cLin, const float* __restrict__ cHin,
    const float* __restrict__ yL,  const float* __restrict__ yH,
    const float* __restrict__ dinv2,
    float* __restrict__ cLout, float* __restrict__ cHout,
    const int* __restrict__ csr, const int* __restrict__ off, int N)
{
  int bid = blockIdx.x;
  int half = (bid & 7) >> 2;
  int node_blk = ((bid >> 3) << 2) | (bid & 3);
  int t = threadIdx.x;
  int n = node_blk*128 + (t >> 1);
  int q = t & 1;
  if (n >= N) return;
  const float4* cin = (const float4*)(half ? cHin : cLin);
  const float4* yin = (const float4*)(half ? yH : yL);
  float4* cout = (float4*)(half ? cHout : cLout);

  float4 a0 = make_float4(0.f,0.f,0.f,0.f);
  float4 a1 = make_float4(0.f,0.f,0.f,0.f);
  float4 a2 = make_float4(0.f,0.f,0.f,0.f);
  float4 a3 = make_float4(0.f,0.f,0.f,0.f);
  int s = off[n], e = off[n+1];
  int i = s;
  for (; i+8 <= e; i += 8){
    int s0 = csr[i],   s1 = csr[i+1], s2 = csr[i+2], s3 = csr[i+3];
    int s4 = csr[i+4], s5 = csr[i+5], s6 = csr[i+6], s7 = csr[i+7];
    float4 v0 = cin[(size_t)s0*2 + q];
    float4 v1 = cin[(size_t)s1*2 + q];
    float4 v2 = cin[(size_t)s2*2 + q];
    float4 v3 = cin[(size_t)s3*2 + q];
    float4 v4 = cin[(size_t)s4*2 + q];
    float4 v5 = cin[(size_t)s5*2 + q];
    float4 v6 = cin[(size_t)s6*2 + q];
    float4 v7 = cin[(size_t)s7*2 + q];
    a0.x += v0.x; a0.y += v0.y; a0.z += v0.z; a0.w += v0.w;
    a1.x += v1.x; a1.y += v1.y; a1.z += v1.z; a1.w += v1.w;
    a2.x += v2.x; a2.y += v2.y; a2.z += v2.z; a2.w += v2.w;
    a3.x += v3.x; a3.y += v3.y; a3.z += v3.z; a3.w += v3.w;
    a0.x += v4.x; a0.y += v4.y; a0.z += v4.z; a0.w += v4.w;
    a1.x += v5.x; a1.y += v5.y; a1.z += v5.z; a1.w += v5.w;
    a2.x += v6.x; a2.y += v6.y; a2.z += v6.z; a2.w += v6.w;
    a3.x += v7.x; a3.y += v7.y; a3.z += v7.z; a3.w += v7.w;
  }
  for (; i+2 <= e; i += 2){
    int s0 = csr[i], s1 = csr[i+1];
    float4 v0 = cin[(size_t)s0*2 + q];
    float4 v1 = cin[(size_t)s1*2 + q];
    a0.x += v0.x; a0.y += v0.y; a0.z += v0.z; a0.w += v0.w;
    a1.x += v1.x; a1.y += v1.y; a1.z += v1.z; a1.w += v1.w;
  }
  if (i < e){
    float4 v0 = cin[(size_t)csr[i]*2 + q];
    a0.x += v0.x; a0.y += v0.y; a0.z += v0.z; a0.w += v0.w;
  }
  float w9 = 0.9f * dinv2[n];
  float4 yv = yin[(size_t)n*2 + q];
  float4 o;
  o.x = fmaf(w9, (a0.x+a1.x)+(a2.x+a3.x), yv.x);
  o.y = fmaf(w9, (a0.y+a1.y)+(a2.y+a3.y), yv.y);
  o.z = fmaf(w9, (a0.z+a1.z)+(a2.z+a3.z), yv.z);
  o.w = fmaf(w9, (a0.w+a1.w)+(a2.w+a3.w), yv.w);
  cout[(size_t)n*2 + q] = o;
}

// ---- last iteration fused with alpha/soft/argmax: beta = 0.9*dinv*sum + 0.1*x0 ----
__global__ __launch_bounds__(256) void k_prop_final(
    const float* __restrict__ cLin, const float* __restrict__ cHin,
    const float* __restrict__ x0, const float* __restrict__ dinv,
    const int* __restrict__ csr, const int* __restrict__ off,
    float* __restrict__ out, int N)
{
  int t = blockIdx.x*256 + threadIdx.x;
  int n = t >> 2, q = t & 3;
  if (n >= N) return;
  const float4* cin = (const float4*)((q < 2) ? cLin : cHin);
  int qq = q & 1;
  float4 a0 = make_float4(0.f,0.f,0.f,0.f);
  float4 a1 = make_float4(0.f,0.f,0.f,0.f);
  float4 a2 = make_float4(0.f,0.f,0.f,0.f);
  float4 a3 = make_float4(0.f,0.f,0.f,0.f);
  int s = off[n], e = off[n+1];
  int i = s;
  for (; i+4 <= e; i += 4){
    int s0 = csr[i], s1 = csr[i+1], s2 = csr[i+2], s3 = csr[i+3];
    float4 v0 = cin[(size_t)s0*2 + qq];
    float4 v1 = cin[(size_t)s1*2 + qq];
    float4 v2 = cin[(size_t)s2*2 + qq];
    float4 v3 = cin[(size_t)s3*2 + qq];
    a0.x += v0.x; a0.y += v0.y; a0.z += v0.z; a0.w += v0.w;
    a1.x += v1.x; a1.y += v1.y; a1.z += v1.z; a1.w += v1.w;
    a2.x += v2.x; a2.y += v2.y; a2.z += v2.z; a2.w += v2.w;
    a3.x += v3.x; a3.y += v3.y; a3.z += v3.z; a3.w += v3.w;
  }
  for (; i < e; ++i){
    float4 v0 = cin[(size_t)csr[i]*2 + qq];
    a0.x += v0.x; a0.y += v0.y; a0.z += v0.z; a0.w += v0.w;
  }
  float w9 = 0.9f * dinv[n];
  float4 xv = ((const float4*)x0)[(size_t)n*4 + q];
  float4 al;
  al.x = fmaf(w9, (a0.x+a1.x)+(a2.x+a3.x), fmaf(0.1f, xv.x, 1.f));
  al.y = fmaf(w9, (a0.y+a1.y)+(a2.y+a3.y), fmaf(0.1f, xv.y, 1.f));
  al.z = fmaf(w9, (a0.z+a1.z)+(a2.z+a3.z), fmaf(0.1f, xv.z, 1.f));
  al.w = fmaf(w9, (a0.w+a1.w)+(a2.w+a3.w), fmaf(0.1f, xv.w, 1.f));

  float sv = 0.f;
  if (q < 2)       sv = al.x + al.y + al.z + al.w;
  else if (q == 2) sv = al.x + al.y;
  sv += __shfl_xor(sv, 1, 4);
  sv += __shfl_xor(sv, 2, 4);

  float bv = -1e30f; int bi = 999;
  int cb = q*4;
  int nvalid = (q < 2) ? 4 : (q == 2 ? 2 : 0);
  float av[4] = {al.x, al.y, al.z, al.w};
  for (int j = 0; j < nvalid; ++j){
    if (av[j] > bv){ bv = av[j]; bi = cb + j; }
  }
  #pragma unroll
  for (int o = 1; o <= 2; o <<= 1){
    float vo = __shfl_xor(bv, o, 4);
    int  io  = __shfl_xor(bi, o, 4);
    if (vo > bv || (vo == bv && io < bi)){ bv = vo; bi = io; }
  }

  float inv = 1.0f / sv;
  size_t sb = (size_t)N + (size_t)n*NC;
  for (int j = 0; j < nvalid; ++j) out[sb + cb + j] = av[j] * inv;
  if (q == 0) out[n] = (float)bi;
}

extern "C" void kernel_launch(void* const* d_in, const int* in_sizes, int n_in,
                              void* d_out, int out_size, void* d_ws, size_t ws_size,
                              hipStream_t stream)
{
  const float* x  = (const float*)d_in[0];
  const int*   ei = (const int*)  d_in[1];
  const float* pc = (const float*)d_in[2];
  const float* W1 = (const float*)d_in[3];
  const float* b1 = (const float*)d_in[4];
  const float* W2 = (const float*)d_in[5];
  const float* b2 = (const float*)d_in[6];
  const float* z0 = (const float*)d_in[7];
  const float* ap = (const float*)d_in[8];
  const float* fb = (const float*)d_in[9];
  float* out = (float*)d_out;

  const int N = in_sizes[0] / DF;
  const int E = in_sizes[1] / 2;
  const int* src = ei;
  const int* dst = ei + E;
  const int B = (N + BW - 1) >> BSH;

  // Workspace. region0 holds bp (E ints) during CSR build, then z (N*16 f32).
  char* ws = (char*)d_ws;
  size_t o = 0;
  size_t region0 = (size_t)E*sizeof(int);
  if ((size_t)N*DL*sizeof(float) > region0) region0 = (size_t)N*DL*sizeof(float);
  int*   bp   = (int*)  (ws + o);
  float* z    = (float*)(ws + o);
  o += region0;
  int*   csr  = (int*)  (ws + o); o += (size_t)(E+N)*sizeof(int);   // +N self edges
  float* x0   = (float*)(ws + o); o += (size_t)N*DL*sizeof(float);
  size_t h8 = (size_t)N*8*sizeof(float);
  float* cL0  = (float*)(ws + o); o += h8;
  float* cH0  = (float*)(ws + o); o += h8;
  float* yL   = (float*)(ws + o); o += h8;
  float* yH   = (float*)(ws + o); o += h8;
  float* cLA  = (float*)(ws + o); o += h8;
  float* cHA  = (float*)(ws + o); o += h8;
  float* cLB  = (float*)(ws + o); o += h8;
  float* cHB  = (float*)(ws + o); o += h8;
  int*   deg  = (int*)  (ws + o); o += (size_t)N*sizeof(int);
  float* dinv = (float*)(ws + o); o += (size_t)N*sizeof(float);
  float* dinv2= (float*)(ws + o); o += (size_t)N*sizeof(float);
  int*   offs = (int*)  (ws + o); o += (size_t)(N+2)*sizeof(int);
  int*   part = (int*)  (ws + o); o += 4096;
  int*   bCnt = (int*)  (ws + o); o += MAXB*sizeof(int);
  int*   bOff = (int*)  (ws + o); o += (MAXB+1)*sizeof(int);
  int*   bCur = (int*)  (ws + o); o += MAXB*sizeof(int);

  const int TB = 256;
  int nb  = (N + 1023) / 1024;

  // Phase 1: bucketed CSR build (bp lives in region0)
  hipMemsetAsync(bCnt, 0, MAXB*sizeof(int), stream);
  hipMemsetAsync(bCur, 0, MAXB*sizeof(int), stream);
  k_bhist<<<512, TB, 0, stream>>>(dst, bCnt, E, B);
  k_bscan<<<1, 1, 0, stream>>>(bCnt, bOff, B);
  k_bscatter<<<(E + TILE - 1)/TILE, TB, 0, stream>>>(src, dst, bOff, bCur, bp, E, B);
  k_bdeg<<<B, TB, 0, stream>>>(bp, bOff, deg, dinv, dinv2, N);
  k_scan_part<<<nb, TB, 0, stream>>>(deg, part, N);
  k_scan_top<<<1, 1, 0, stream>>>(part, nb);
  k_scan_final<<<nb, TB, 0, stream>>>(deg, part, offs, N, E);
  k_place<<<B, TB, 0, stream>>>(bp, bOff, offs, csr, N);
  k_rank<<<(N + 3) / 4, TB, 0, stream>>>(csr, offs, N);

  // Phase 2: encoder fused with z projection (z overwrites bp), then flows
  k_gemm1z<<<(N + BM - 1) / BM, TB, 0, stream>>>(x, W1, b1, W2, b2, z, N);
  k_flow2<<<((N*DL) + TB - 1) / TB, TB, 0, stream>>>(z, pc, z0, ap, fb, dinv,
                                                     x0, cL0, cH0, yL, yH, N);

  // Phase 3: APPNP in c-space, class-split + XCD-steered.
  int P = (N + 127) / 128;                 // node-blocks per half
  int gH = 8 * ((P + 3) / 4);              // grid covering both halves
  const float* cLin = cL0; const float* cHin = cH0;
  for (int it = 0; it < KPROP-1; ++it){
    float* cLo = (it & 1) ? cLB : cLA;
    float* cHo = (it & 1) ? cHB : cHA;
    k_prop_half<<<gH, TB, 0, stream>>>(cLin, cHin, yL, yH, dinv2, cLo, cHo,
                                       csr, offs, N);
    cLin = cLo; cHin = cHo;
  }
  int gF = ((N*4) + TB - 1) / TB;
  k_prop_final<<<gF, TB, 0, stream>>>(cLin, cHin, x0, dinv, csr, offs, out, N);
}

// Round 9
// 807.151 us; speedup vs baseline: 1.1403x; 1.1403x over previous
//
#include <hip/hip_runtime.h>
#include <math.h>
#include <limits.h>

#define DF 512
#define DH 64
#define DL 16
#define NC 10
#define NF 10
#define KPROP 10

#define BSH 7                  // bucket shift: 128 nodes per bucket
#define BW  (1 << BSH)
#define MAXB 1024
#define TILE 16384
#define TS 16384               // prop source-tile: 16384 nodes = 1MB of c

__device__ __forceinline__ float softplus_(float x){
  return fmaxf(x, 0.0f) + log1pf(expf(-fabsf(x)));
}

// -------- GEMM1 fused with z-projection: z = relu(x@W1+b1) @ W2 + b2 --------
// 128x64 tile, 256 threads, 8x4 microtile, BK=16. 17.6KB LDS, reg epilogue.
#define BM 128
#define BK2 16
__global__ __launch_bounds__(256) void k_gemm1z(const float* __restrict__ x,
    const float* __restrict__ W1, const float* __restrict__ b1,
    const float* __restrict__ W2, const float* __restrict__ b2,
    float* __restrict__ z, int N)
{
  __shared__ float At[BK2][132];   // x tile transposed [kk][row]
  __shared__ float Bs[BK2][68];    // W1 tile [kk][col]
  __shared__ float W2s[DH][20];    // stride 20: 16B-aligned float4 rows, 2-way banks
  __shared__ float b2s[DL];
  const int tid = threadIdx.x;
  for (int i = tid; i < DH*DL; i += 256) W2s[i>>4][i&15] = W2[i];
  if (tid < DL) b2s[tid] = b2[tid];
  const int tx = tid & 15, ty = tid >> 4;   // 16 col-groups x 16 row-groups
  const int row0 = blockIdx.x * BM;
  float acc[8][4] = {};
  for (int k0 = 0; k0 < DF; k0 += BK2){
    // stage x tile: 128 rows x 16 k = 512 float4, 2 per thread
    #pragma unroll
    for (int j = 0; j < 2; ++j){
      int s_ = tid + j*256;
      int r  = s_ >> 2;                 // 0..127
      int k4 = (s_ & 3) << 2;           // 0,4,8,12
      int row = row0 + r;
      float4 va = make_float4(0.f,0.f,0.f,0.f);
      if (row < N) va = *(const float4*)&x[(size_t)row*DF + k0 + k4];
      At[k4+0][r]=va.x; At[k4+1][r]=va.y; At[k4+2][r]=va.z; At[k4+3][r]=va.w;
    }
    // stage W1 tile: 16 x 64 = 256 float4, 1 per thread
    {
      int kk = tid >> 4, c4 = (tid & 15) << 2;
      float4 vb = *(const float4*)&W1[(size_t)(k0+kk)*DH + c4];
      *(float4*)&Bs[kk][c4] = vb;
    }
    __syncthreads();
    #pragma unroll
    for (int kk = 0; kk < BK2; ++kk){
      float4 a0 = *(const float4*)&At[kk][ty*8];
      float4 a1 = *(const float4*)&At[kk][ty*8+4];
      float4 bv = *(const float4*)&Bs[kk][tx*4];
      float a8[8] = {a0.x,a0.y,a0.z,a0.w,a1.x,a1.y,a1.z,a1.w};
      float b4[4] = {bv.x,bv.y,bv.z,bv.w};
      #pragma unroll
      for (int i=0;i<8;++i)
        #pragma unroll
        for (int j=0;j<4;++j) acc[i][j] = fmaf(a8[i], b4[j], acc[i][j]);
    }
    __syncthreads();
  }
  // bias + relu in registers
  float4 bias = ((const float4*)b1)[tx];
  float bb[4] = {bias.x, bias.y, bias.z, bias.w};
  #pragma unroll
  for (int i=0;i<8;++i)
    #pragma unroll
    for (int j=0;j<4;++j) acc[i][j] = fmaxf(acc[i][j] + bb[j], 0.0f);

  // z = h@W2: per row, partials over my 4 h-cols, width-16 shuffle reduce
  #pragma unroll 1
  for (int r = 0; r < 8; ++r){
    float zp[16];
    #pragma unroll
    for (int zc=0; zc<16; ++zc) zp[zc] = 0.f;
    #pragma unroll
    for (int j=0; j<4; ++j){
      int c = tx*4 + j;
      float h = acc[r][j];
      float4 w0 = *(const float4*)&W2s[c][0];
      float4 w1 = *(const float4*)&W2s[c][4];
      float4 w2 = *(const float4*)&W2s[c][8];
      float4 w3 = *(const float4*)&W2s[c][12];
      zp[0]=fmaf(h,w0.x,zp[0]);  zp[1]=fmaf(h,w0.y,zp[1]);
      zp[2]=fmaf(h,w0.z,zp[2]);  zp[3]=fmaf(h,w0.w,zp[3]);
      zp[4]=fmaf(h,w1.x,zp[4]);  zp[5]=fmaf(h,w1.y,zp[5]);
      zp[6]=fmaf(h,w1.z,zp[6]);  zp[7]=fmaf(h,w1.w,zp[7]);
      zp[8]=fmaf(h,w2.x,zp[8]);  zp[9]=fmaf(h,w2.y,zp[9]);
      zp[10]=fmaf(h,w2.z,zp[10]); zp[11]=fmaf(h,w2.w,zp[11]);
      zp[12]=fmaf(h,w3.x,zp[12]); zp[13]=fmaf(h,w3.y,zp[13]);
      zp[14]=fmaf(h,w3.z,zp[14]); zp[15]=fmaf(h,w3.w,zp[15]);
    }
    #pragma unroll
    for (int zc=0; zc<16; ++zc){
      float v = zp[zc];
      v += __shfl_xor(v, 1, 16);
      v += __shfl_xor(v, 2, 16);
      v += __shfl_xor(v, 4, 16);
      v += __shfl_xor(v, 8, 16);
      zp[zc] = v;
    }
    int grow = row0 + ty*8 + r;
    if (tx < 4 && grow < N){
      float4 o;
      if      (tx == 0) o = make_float4(zp[0]+b2s[0],  zp[1]+b2s[1],  zp[2]+b2s[2],  zp[3]+b2s[3]);
      else if (tx == 1) o = make_float4(zp[4]+b2s[4],  zp[5]+b2s[5],  zp[6]+b2s[6],  zp[7]+b2s[7]);
      else if (tx == 2) o = make_float4(zp[8]+b2s[8],  zp[9]+b2s[9],  zp[10]+b2s[10],zp[11]+b2s[11]);
      else              o = make_float4(zp[12]+b2s[12],zp[13]+b2s[13],zp[14]+b2s[14],zp[15]+b2s[15]);
      ((float4*)z)[(size_t)grow*4 + tx] = o;
    }
  }
}

// -------- radial flows: one thread per (node, class) --------
__global__ __launch_bounds__(256) void k_flow2(const float* __restrict__ z,
    const float* __restrict__ pc, const float* __restrict__ z0g,
    const float* __restrict__ apg, const float* __restrict__ fbg,
    const float* __restrict__ dinv,
    float* __restrict__ x0, float* __restrict__ c0, float* __restrict__ y0, int N)
{
  __shared__ float z0s[NF][NC][DL];
  __shared__ float alps[NF][NC];
  __shared__ float bhs[NF][NC];
  __shared__ float lpc[NC];
  int tid = threadIdx.x;
  for (int i = tid; i < NF*NC*DL; i += 256)
    z0s[(i>>4)/NC][(i>>4)%NC][i&15] = z0g[i];
  if (tid < NF*NC){
    int l = tid/NC, c = tid%NC;
    float al = softplus_(apg[tid]);
    alps[l][c] = al;
    bhs[l][c]  = -al + softplus_(fbg[tid]);
  }
  if (tid < NC) lpc[tid] = __logf(pc[tid]);
  __syncthreads();

  int idx = blockIdx.x*256 + tid;
  int n = idx >> 4, c = idx & 15;
  if (n >= N) return;
  float dn = dinv[n];
  if (c >= NC){ x0[idx] = 0.f; c0[idx] = 0.f; y0[idx] = 0.f; return; }

  float zz[DL];
  const float4* z4 = (const float4*)z;
  #pragma unroll
  for (int q=0; q<4; ++q){
    float4 v = z4[(size_t)n*4 + q];
    zz[q*4+0]=v.x; zz[q*4+1]=v.y; zz[q*4+2]=v.z; zz[q*4+3]=v.w;
  }
  const float NEGHALFD_LOG2PI = -14.703016531274762f;  // -8*log(2*pi)
  const float LOGSCALE        =  20.248193975754326f;  //  8*log(4*pi)
  float sld = 0.f;
  #pragma unroll 1
  for (int l=0; l<NF; ++l){
    float al = alps[l][c], bhat = bhs[l][c];
    float dz[DL]; float r2 = 0.f;
    #pragma unroll
    for (int d=0; d<DL; ++d){ float t = zz[d] - z0s[l][c][d]; dz[d]=t; r2 = fmaf(t,t,r2); }
    float r  = sqrtf(r2);
    float hh = 1.0f/(al + r);
    float bh = bhat*hh;
    #pragma unroll
    for (int d=0; d<DL; ++d) zz[d] = fmaf(bh, dz[d], zz[d]);
    sld += 15.0f*__logf(1.0f + bh) + __logf(1.0f + bh - bhat*r*hh*hh);
  }
  float q2 = 0.f;
  #pragma unroll
  for (int d=0; d<DL; ++d) q2 = fmaf(zz[d], zz[d], q2);
  float v = -0.5f*q2 + NEGHALFD_LOG2PI + sld + lpc[c] + LOGSCALE;
  v = fminf(fmaxf(v, -30.f), 30.f);
  float xv = __expf(v);
  x0[idx] = xv;
  c0[idx] = dn*xv;
  y0[idx] = 0.1f*dn*xv;
}

// ---------------- bucketed CSR construction ----------------
__global__ __launch_bounds__(256) void k_bhist(const int* __restrict__ dst,
    int* __restrict__ bCnt, int E, int B)
{
  __shared__ int hh[MAXB];
  int tid = threadIdx.x;
  for (int b = tid; b < B; b += 256) hh[b] = 0;
  __syncthreads();
  for (int i = blockIdx.x*256 + tid; i < E; i += gridDim.x*256)
    atomicAdd(&hh[dst[i] >> BSH], 1);
  __syncthreads();
  for (int b = tid; b < B; b += 256) if (hh[b]) atomicAdd(&bCnt[b], hh[b]);
}

__global__ void k_bscan(const int* __restrict__ bCnt, int* __restrict__ bOff, int B){
  if (blockIdx.x==0 && threadIdx.x==0){
    int run = 0;
    for (int b=0;b<B;++b){ bOff[b]=run; run+=bCnt[b]; }
    bOff[B]=run;
  }
}

__global__ __launch_bounds__(256) void k_bscatter(const int* __restrict__ src,
    const int* __restrict__ dst, const int* __restrict__ bOff,
    int* __restrict__ bCur, int* __restrict__ bp, int E, int B)
{
  __shared__ int hc[MAXB];
  __shared__ int hb[MAXB];
  int tid = threadIdx.x;
  int base = blockIdx.x * TILE;
  int lim  = base + TILE; if (lim > E) lim = E;
  for (int b = tid; b < B; b += 256) hc[b] = 0;
  __syncthreads();
  for (int i = base + tid; i < lim; i += 256)
    atomicAdd(&hc[dst[i] >> BSH], 1);
  __syncthreads();
  for (int b = tid; b < B; b += 256){
    int c = hc[b];
    hb[b] = c ? atomicAdd(&bCur[b], c) : 0;
    hc[b] = 0;
  }
  __syncthreads();
  for (int i = base + tid; i < lim; i += 256){
    int d = dst[i];
    int b = d >> BSH;
    int pos = bOff[b] + hb[b] + atomicAdd(&hc[b], 1);
    bp[pos] = (src[i] << BSH) | (d & (BW-1));
  }
}

// per-bucket in-degree count (+1 self loop) fused with dinv/dinv2
__global__ __launch_bounds__(256) void k_bdeg(const int* __restrict__ bp,
    const int* __restrict__ bOff, int* __restrict__ deg,
    float* __restrict__ dinv, float* __restrict__ dinv2, int N)
{
  __shared__ int cur[BW];
  int tid = threadIdx.x;
  int b = blockIdx.x;
  if (tid < BW) cur[tid] = 0;
  __syncthreads();
  int s = bOff[b], e = bOff[b+1];
  for (int i = s + tid; i < e; i += 256)
    atomicAdd(&cur[bp[i] & (BW-1)], 1);
  __syncthreads();
  int node = (b << BSH) + tid;
  if (tid < BW && node < N){
    int d = cur[tid] + 1;                 // +1 self loop
    deg[node] = d;
    float dv = 1.0f / sqrtf((float)d);
    dinv[node]  = dv;
    dinv2[node] = dv*dv;
  }
}

__global__ __launch_bounds__(256) void k_scan_part(const int* __restrict__ deg,
    int* __restrict__ part, int N){
  __shared__ int sd[256];
  int base = blockIdx.x*1024;
  int tid = threadIdx.x;
  int s = 0;
  #pragma unroll
  for (int i=0;i<4;++i){ int idx = base + tid*4 + i; if (idx < N) s += deg[idx]; }
  sd[tid] = s; __syncthreads();
  for (int ofs=128; ofs>0; ofs>>=1){ if (tid<ofs) sd[tid]+=sd[tid+ofs]; __syncthreads(); }
  if (tid==0) part[blockIdx.x] = sd[0];
}

__global__ void k_scan_top(int* part, int nb){
  if (blockIdx.x==0 && threadIdx.x==0){
    int run = 0;
    for (int i=0;i<nb;++i){ int v = part[i]; part[i] = run; run += v; }
  }
}

__global__ __launch_bounds__(256) void k_scan_final(const int* __restrict__ deg,
    const int* __restrict__ part, int* __restrict__ off, int N, int E)
{
  __shared__ int sc[256];
  int base = blockIdx.x*1024;
  int tid = threadIdx.x;
  int v[4]; int s = 0;
  #pragma unroll
  for (int i=0;i<4;++i){ int idx = base + tid*4 + i; v[i] = (idx<N)?deg[idx]:0; s += v[i]; }
  sc[tid] = s; __syncthreads();
  for (int ofs=1; ofs<256; ofs<<=1){
    int t = (tid>=ofs) ? sc[tid-ofs] : 0;
    __syncthreads();
    sc[tid] += t;
    __syncthreads();
  }
  int ex = sc[tid] - s + part[blockIdx.x];
  #pragma unroll
  for (int i=0;i<4;++i){
    int idx = base + tid*4 + i;
    if (idx < N){
      off[idx] = ex;
      if (idx == N-1) off[N] = ex + v[i];
      ex += v[i];
    }
  }
}

// place self edge (slot 0) + src ints at CSR positions
__global__ __launch_bounds__(256) void k_place(const int* __restrict__ bp,
    const int* __restrict__ bOff, const int* __restrict__ off,
    int* __restrict__ csr, int N)
{
  __shared__ int cur[BW];
  int tid = threadIdx.x;
  int b = blockIdx.x;
  int node0 = b << BSH;
  if (tid < BW){
    cur[tid] = 1;                                 // slot 0 reserved for self
    int node = node0 + tid;
    if (node < N) csr[off[node]] = node;
  }
  __syncthreads();
  int s = bOff[b], e = bOff[b+1];
  for (int i = s + tid; i < e; i += 256){
    int v  = bp[i];
    int dl = v & (BW-1);
    int sn = v >> BSH;
    int d  = node0 + dl;
    int p  = off[d] + atomicAdd(&cur[dl], 1);
    csr[p] = sn;
  }
}

// ---- canonicalize segment order (stable value-rank via shuffles) ----
// Also emits per-node source-tile boundaries tb[n][t] = #edges with src <
// (t+1)*TS for t=0..6, tb[n][7] = degree (ushort, 16B/node).
__global__ __launch_bounds__(256) void k_rank(int* __restrict__ csr,
    const int* __restrict__ off, unsigned short* __restrict__ tb, int N)
{
  int wid  = (blockIdx.x*256 + threadIdx.x) >> 6;
  int lane = threadIdx.x & 63;
  if (wid >= N) return;
  int s = off[wid], e = off[wid+1];
  int d = e - s;
  if (d <= 0){
    if (lane < 8) tb[(size_t)wid*8 + lane] = 0;
    return;
  }
  if (d <= 64){
    int v = (lane < d) ? csr[s+lane] : INT_MAX;
    int rank = 0;
    for (int j = 0; j < d; ++j){
      int bv = __shfl(v, j);
      rank += (bv < v) || (bv == v && j < lane);
    }
    if (lane < d) csr[s+rank] = v;
    unsigned int myc = (unsigned)d;
    #pragma unroll
    for (int t = 0; t < 7; ++t){
      unsigned long long m = __ballot((lane < d) && (v < (t+1)*TS));
      if (lane == t) myc = (unsigned)__popcll(m);
    }
    if (lane < 8) tb[(size_t)wid*8 + lane] = (unsigned short)((lane < 7) ? myc : (unsigned)d);
  } else if (d <= 256){
    int v0 = (lane      < d) ? csr[s+lane      ] : INT_MAX;
    int v1 = (lane+64   < d) ? csr[s+lane+64   ] : INT_MAX;
    int v2 = (lane+128  < d) ? csr[s+lane+128  ] : INT_MAX;
    int v3 = (lane+192  < d) ? csr[s+lane+192  ] : INT_MAX;
    int r0=0,r1=0,r2=0,r3=0;
    for (int j = 0; j < d; ++j){
      int slot = j >> 6, jl = j & 63;
      int bv = (slot==0) ? __shfl(v0,jl) : (slot==1) ? __shfl(v1,jl)
             : (slot==2) ? __shfl(v2,jl) : __shfl(v3,jl);
      r0 += (bv < v0) || (bv == v0 && j < lane);
      r1 += (bv < v1) || (bv == v1 && j < lane+64);
      r2 += (bv < v2) || (bv == v2 && j < lane+128);
      r3 += (bv < v3) || (bv == v3 && j < lane+192);
    }
    if (lane      < d) csr[s+r0]=v0;
    if (lane+64   < d) csr[s+r1]=v1;
    if (lane+128  < d) csr[s+r2]=v2;
    if (lane+192  < d) csr[s+r3]=v3;
    unsigned int myc = (unsigned)d;
    #pragma unroll
    for (int t = 0; t < 7; ++t){
      int lim = (t+1)*TS;
      unsigned long long m0 = __ballot((lane      < d) && (v0 < lim));
      unsigned long long m1 = __ballot((lane+64   < d) && (v1 < lim));
      unsigned long long m2 = __ballot((lane+128  < d) && (v2 < lim));
      unsigned long long m3 = __ballot((lane+192  < d) && (v3 < lim));
      if (lane == t)
        myc = (unsigned)(__popcll(m0)+__popcll(m1)+__popcll(m2)+__popcll(m3));
    }
    if (lane < 8) tb[(size_t)wid*8 + lane] = (unsigned short)((lane < 7) ? myc : (unsigned)d);
  } else {
    if (lane == 0){
      for (int i = s+1; i < e; ++i){
        int key = csr[i]; int j = i-1;
        while (j >= s && csr[j] > key){ csr[j+1] = csr[j]; --j; }
        csr[j+1] = key;
      }
      for (int t = 0; t < 7; ++t){
        int lim = (t+1)*TS;
        int c = 0;
        for (int i = s; i < e; ++i) c += (csr[i] < lim);
        tb[(size_t)wid*8 + t] = (unsigned short)c;
      }
      tb[(size_t)wid*8 + 7] = (unsigned short)d;
    }
  }
}

// ---- APPNP c-space iteration, src-tiled: c' = 0.9*dinv2*sum(c[src]) + y0 ----
// Tile t covers sources [t*TS,(t+1)*TS) = 1MB of c -> L2-resident window.
// Block-wide barrier per tile bounds intra-block drift. Ascending order kept
// (bit-deterministic). No early returns (barrier safety).
__global__ __launch_bounds__(256) void k_prop(const float* __restrict__ cin,
    const float* __restrict__ y0, const float* __restrict__ dinv2,
    float* __restrict__ cout, const int* __restrict__ csr,
    const int* __restrict__ off, const unsigned short* __restrict__ tb,
    int N, int NT)
{
  int t0 = blockIdx.x*256 + threadIdx.x;
  int n = t0 >> 2, q = t0 & 3;
  bool valid = (n < N);
  int nc = valid ? n : (N-1);
  const float4* c4 = (const float4*)cin;
  float4 a = make_float4(0.f,0.f,0.f,0.f);
  int s = off[nc], e = off[nc+1];
  uint4 bw = *(const uint4*)(tb + (size_t)nc*8);
  if (!valid) e = s;
  int i = s;
  #pragma unroll
  for (int t = 0; t < 8; ++t){
    if (t < NT){
      int lim;
      if (t == NT-1) lim = e;
      else {
        unsigned w = (t < 2) ? bw.x : (t < 4) ? bw.y : (t < 6) ? bw.z : bw.w;
        unsigned c = (t & 1) ? (w >> 16) : (w & 0xffffu);
        lim = s + (int)c;
        if (lim > e) lim = e;
      }
      for (; i+4 <= lim; i += 4){
        int s0=csr[i], s1=csr[i+1], s2=csr[i+2], s3=csr[i+3];
        float4 v0 = c4[(size_t)s0*4 + q];
        float4 v1 = c4[(size_t)s1*4 + q];
        float4 v2 = c4[(size_t)s2*4 + q];
        float4 v3 = c4[(size_t)s3*4 + q];
        a.x+=v0.x; a.y+=v0.y; a.z+=v0.z; a.w+=v0.w;
        a.x+=v1.x; a.y+=v1.y; a.z+=v1.z; a.w+=v1.w;
        a.x+=v2.x; a.y+=v2.y; a.z+=v2.z; a.w+=v2.w;
        a.x+=v3.x; a.y+=v3.y; a.z+=v3.z; a.w+=v3.w;
      }
      for (; i < lim; ++i){
        float4 v = c4[(size_t)csr[i]*4 + q];
        a.x+=v.x; a.y+=v.y; a.z+=v.z; a.w+=v.w;
      }
      __syncthreads();
    }
  }
  if (valid){
    float w9 = 0.9f * dinv2[n];
    float4 yv = ((const float4*)y0)[(size_t)n*4 + q];
    float4 o;
    o.x = fmaf(w9, a.x, yv.x);
    o.y = fmaf(w9, a.y, yv.y);
    o.z = fmaf(w9, a.z, yv.z);
    o.w = fmaf(w9, a.w, yv.w);
    ((float4*)cout)[(size_t)n*4 + q] = o;
  }
}

// ---- last iteration fused with alpha/soft/argmax (src-tiled too) ----
__global__ __launch_bounds__(256) void k_prop_final(const float* __restrict__ cin,
    const float* __restrict__ x0, const float* __restrict__ dinv,
    const int* __restrict__ csr, const int* __restrict__ off,
    const unsigned short* __restrict__ tb,
    float* __restrict__ out, int N, int NT)
{
  int t0 = blockIdx.x*256 + threadIdx.x;
  int n = t0 >> 2, q = t0 & 3;
  bool valid = (n < N);
  int nc = valid ? n : (N-1);
  const float4* c4 = (const float4*)cin;
  float4 a = make_float4(0.f,0.f,0.f,0.f);
  int s = off[nc], e = off[nc+1];
  uint4 bw = *(const uint4*)(tb + (size_t)nc*8);
  if (!valid) e = s;
  int i = s;
  #pragma unroll
  for (int t = 0; t < 8; ++t){
    if (t < NT){
      int lim;
      if (t == NT-1) lim = e;
      else {
        unsigned w = (t < 2) ? bw.x : (t < 4) ? bw.y : (t < 6) ? bw.z : bw.w;
        unsigned c = (t & 1) ? (w >> 16) : (w & 0xffffu);
        lim = s + (int)c;
        if (lim > e) lim = e;
      }
      for (; i+4 <= lim; i += 4){
        int s0=csr[i], s1=csr[i+1], s2=csr[i+2], s3=csr[i+3];
        float4 v0 = c4[(size_t)s0*4 + q];
        float4 v1 = c4[(size_t)s1*4 + q];
        float4 v2 = c4[(size_t)s2*4 + q];
        float4 v3 = c4[(size_t)s3*4 + q];
        a.x+=v0.x; a.y+=v0.y; a.z+=v0.z; a.w+=v0.w;
        a.x+=v1.x; a.y+=v1.y; a.z+=v1.z; a.w+=v1.w;
        a.x+=v2.x; a.y+=v2.y; a.z+=v2.z; a.w+=v2.w;
        a.x+=v3.x; a.y+=v3.y; a.z+=v3.z; a.w+=v3.w;
      }
      for (; i < lim; ++i){
        float4 v = c4[(size_t)csr[i]*4 + q];
        a.x+=v.x; a.y+=v.y; a.z+=v.z; a.w+=v.w;
      }
      __syncthreads();
    }
  }
  if (!valid) return;
  float w9 = 0.9f * dinv[n];
  float4 xv = ((const float4*)x0)[(size_t)n*4 + q];
  float4 al;
  al.x = fmaf(w9, a.x, fmaf(0.1f, xv.x, 1.f));
  al.y = fmaf(w9, a.y, fmaf(0.1f, xv.y, 1.f));
  al.z = fmaf(w9, a.z, fmaf(0.1f, xv.z, 1.f));
  al.w = fmaf(w9, a.w, fmaf(0.1f, xv.w, 1.f));

  float sv = 0.f;
  if (q < 2)       sv = al.x + al.y + al.z + al.w;
  else if (q == 2) sv = al.x + al.y;
  sv += __shfl_xor(sv, 1, 4);
  sv += __shfl_xor(sv, 2, 4);

  float bv = -1e30f; int bi = 999;
  int cb = q*4;
  int nvalid = (q < 2) ? 4 : (q == 2 ? 2 : 0);
  float av[4] = {al.x, al.y, al.z, al.w};
  for (int j = 0; j < nvalid; ++j){
    if (av[j] > bv){ bv = av[j]; bi = cb + j; }
  }
  #pragma unroll
  for (int o = 1; o <= 2; o <<= 1){
    float vo = __shfl_xor(bv, o, 4);
    int  io  = __shfl_xor(bi, o, 4);
    if (vo > bv || (vo == bv && io < bi)){ bv = vo; bi = io; }
  }

  float inv = 1.0f / sv;
  size_t sb = (size_t)N + (size_t)n*NC;
  for (int j = 0; j < nvalid; ++j) out[sb + cb + j] = av[j] * inv;
  if (q == 0) out[n] = (float)bi;
}

extern "C" void kernel_launch(void* const* d_in, const int* in_sizes, int n_in,
                              void* d_out, int out_size, void* d_ws, size_t ws_size,
                              hipStream_t stream)
{
  const float* x  = (const float*)d_in[0];
  const int*   ei = (const int*)  d_in[1];
  const float* pc = (const float*)d_in[2];
  const float* W1 = (const float*)d_in[3];
  const float* b1 = (const float*)d_in[4];
  const float* W2 = (const float*)d_in[5];
  const float* b2 = (const float*)d_in[6];
  const float* z0 = (const float*)d_in[7];
  const float* ap = (const float*)d_in[8];
  const float* fb = (const float*)d_in[9];
  float* out = (float*)d_out;

  const int N = in_sizes[0] / DF;
  const int E = in_sizes[1] / 2;
  const int* src = ei;
  const int* dst = ei + E;
  const int B = (N + BW - 1) >> BSH;
  const int NT = (N + TS - 1) / TS;     // source tiles (<=8 for N<=131072)

  // Workspace. region0 holds bp (E ints) during CSR build, then z (N*16 f32).
  char* ws = (char*)d_ws;
  size_t o = 0;
  size_t region0 = (size_t)E*sizeof(int);
  if ((size_t)N*DL*sizeof(float) > region0) region0 = (size_t)N*DL*sizeof(float);
  int*   bp   = (int*)  (ws + o);
  float* z    = (float*)(ws + o);
  o += region0;
  int*   csr  = (int*)  (ws + o); o += (size_t)(E+N)*sizeof(int);   // +N self edges
  float* x0   = (float*)(ws + o); o += (size_t)N*DL*sizeof(float);
  float* c0   = (float*)(ws + o); o += (size_t)N*DL*sizeof(float);
  float* y0   = (float*)(ws + o); o += (size_t)N*DL*sizeof(float);
  float* cA   = (float*)(ws + o); o += (size_t)N*DL*sizeof(float);
  float* cB   = (float*)(ws + o); o += (size_t)N*DL*sizeof(float);
  int*   deg  = (int*)  (ws + o); o += (size_t)N*sizeof(int);
  float* dinv = (float*)(ws + o); o += (size_t)N*sizeof(float);
  float* dinv2= (float*)(ws + o); o += (size_t)N*sizeof(float);
  unsigned short* tb = (unsigned short*)(ws + o); o += (size_t)N*8*sizeof(unsigned short);
  int*   offs = (int*)  (ws + o); o += (size_t)(N+2)*sizeof(int);
  int*   part = (int*)  (ws + o); o += 4096;
  int*   bCnt = (int*)  (ws + o); o += MAXB*sizeof(int);
  int*   bOff = (int*)  (ws + o); o += (MAXB+1)*sizeof(int);
  int*   bCur = (int*)  (ws + o); o += MAXB*sizeof(int);

  const int TB = 256;
  int nb  = (N + 1023) / 1024;

  // Phase 1: bucketed CSR build (bp lives in region0)
  hipMemsetAsync(bCnt, 0, MAXB*sizeof(int), stream);
  hipMemsetAsync(bCur, 0, MAXB*sizeof(int), stream);
  k_bhist<<<512, TB, 0, stream>>>(dst, bCnt, E, B);
  k_bscan<<<1, 1, 0, stream>>>(bCnt, bOff, B);
  k_bscatter<<<(E + TILE - 1)/TILE, TB, 0, stream>>>(src, dst, bOff, bCur, bp, E, B);
  k_bdeg<<<B, TB, 0, stream>>>(bp, bOff, deg, dinv, dinv2, N);
  k_scan_part<<<nb, TB, 0, stream>>>(deg, part, N);
  k_scan_top<<<1, 1, 0, stream>>>(part, nb);
  k_scan_final<<<nb, TB, 0, stream>>>(deg, part, offs, N, E);
  k_place<<<B, TB, 0, stream>>>(bp, bOff, offs, csr, N);
  k_rank<<<(N + 3) / 4, TB, 0, stream>>>(csr, offs, tb, N);

  // Phase 2: encoder fused with z projection (z overwrites bp), then flows
  k_gemm1z<<<(N + BM - 1) / BM, TB, 0, stream>>>(x, W1, b1, W2, b2, z, N);
  k_flow2<<<((N*DL) + TB - 1) / TB, TB, 0, stream>>>(z, pc, z0, ap, fb, dinv,
                                                     x0, c0, y0, N);

  // Phase 3: APPNP in c-space — 9 tiled iterations + 1 fused with epilogue
  int gP = ((N*4) + TB - 1) / TB;
  const float* cin = c0;
  for (int it = 0; it < KPROP-1; ++it){
    float* cout = (it & 1) ? cB : cA;
    k_prop<<<gP, TB, 0, stream>>>(cin, y0, dinv2, cout, csr, offs, tb, N, NT);
    cin = cout;
  }
  k_prop_final<<<gP, TB, 0, stream>>>(cin, x0, dinv, csr, offs, tb, out, N, NT);
}

// Round 10
// 785.204 us; speedup vs baseline: 1.1721x; 1.0280x over previous
//
#include <hip/hip_runtime.h>
#include <math.h>
#include <limits.h>

#define DF 512
#define DH 64
#define DL 16
#define NC 10
#define NF 10
#define KPROP 10

#define BSH 7                  // bucket shift: 128 nodes per bucket
#define BW  (1 << BSH)
#define MAXB 1024
#define TILE 16384
#define TS 16384               // prop source-tile: 16384 nodes = 1MB of c

__device__ __forceinline__ float softplus_(float x){
  return fmaxf(x, 0.0f) + log1pf(expf(-fabsf(x)));
}

// -------- GEMM1 fused with z-projection: z = relu(x@W1+b1) @ W2 + b2 --------
// (round-6 proven config: 64x64 tile, 4x4 microtile, BK=32, 124us, 36 VGPR)
#define BM 64
#define BN 64
#define BK 32
__global__ __launch_bounds__(256) void k_gemm1z(const float* __restrict__ x,
    const float* __restrict__ W1, const float* __restrict__ b1,
    const float* __restrict__ W2, const float* __restrict__ b2,
    float* __restrict__ z, int N)
{
  __shared__ float smem[2*BK*(BM+4)];           // At | Bs, later overlaid by hs[64][68]
  float (*At)[BM+4] = (float(*)[BM+4])smem;
  float (*Bs)[BN+4] = (float(*)[BN+4])(smem + BK*(BM+4));
  __shared__ float W2s[DH][DL];
  __shared__ float b2s[DL];
  const int tid = threadIdx.x;
  for (int i = tid; i < DH*DL; i += 256) W2s[i>>4][i&15] = W2[i];
  if (tid < DL) b2s[tid] = b2[tid];
  const int tx = tid & 15, ty = tid >> 4;
  const int row0 = blockIdx.x * BM;
  float acc[4][4] = {};
  for (int k0 = 0; k0 < DF; k0 += BK) {
    #pragma unroll
    for (int i = 0; i < 2; ++i) {
      int idx = tid + i*256;
      int r  = idx >> 3;
      int kk = (idx & 7) << 2;
      int row = row0 + r;
      float4 va = make_float4(0.f,0.f,0.f,0.f);
      if (row < N) va = *(const float4*)&x[(size_t)row*DF + k0 + kk];
      At[kk+0][r]=va.x; At[kk+1][r]=va.y; At[kk+2][r]=va.z; At[kk+3][r]=va.w;
      int r2 = idx >> 4;
      int c4 = (idx & 15) << 2;
      float4 vb = *(const float4*)&W1[(size_t)(k0+r2)*DH + c4];
      Bs[r2][c4+0]=vb.x; Bs[r2][c4+1]=vb.y; Bs[r2][c4+2]=vb.z; Bs[r2][c4+3]=vb.w;
    }
    __syncthreads();
    #pragma unroll
    for (int kk = 0; kk < BK; ++kk) {
      float4 av = *(const float4*)&At[kk][ty<<2];
      float4 bv = *(const float4*)&Bs[kk][tx<<2];
      float a4[4]={av.x,av.y,av.z,av.w};
      float b4[4]={bv.x,bv.y,bv.z,bv.w};
      #pragma unroll
      for (int i=0;i<4;++i)
        #pragma unroll
        for (int j=0;j<4;++j) acc[i][j] = fmaf(a4[i], b4[j], acc[i][j]);
    }
    __syncthreads();
  }
  // epilogue: h tile -> LDS (overlay), then z = h@W2+b2
  float4 bias = ((const float4*)b1)[tx];
  float bias4[4] = {bias.x, bias.y, bias.z, bias.w};
  float (*hs)[BM+4] = (float(*)[BM+4])smem;
  #pragma unroll
  for (int i=0;i<4;++i){
    #pragma unroll
    for (int j=0;j<4;++j)
      hs[(ty<<2)+i][(tx<<2)+j] = fmaxf(acc[i][j] + bias4[j], 0.0f);
  }
  __syncthreads();
  int row = tid >> 2, lg = tid & 3;
  float4 zacc = ((const float4*)b2s)[lg];
  #pragma unroll 8
  for (int k = 0; k < DH; ++k){
    float hv = hs[row][k];
    float4 wv = *(const float4*)&W2s[k][lg<<2];
    zacc.x = fmaf(hv, wv.x, zacc.x);
    zacc.y = fmaf(hv, wv.y, zacc.y);
    zacc.z = fmaf(hv, wv.z, zacc.z);
    zacc.w = fmaf(hv, wv.w, zacc.w);
  }
  int grow = row0 + row;
  if (grow < N) ((float4*)z)[(size_t)grow*4 + lg] = zacc;
}

// -------- radial flows: one thread per (node, class) --------
__global__ __launch_bounds__(256) void k_flow2(const float* __restrict__ z,
    const float* __restrict__ pc, const float* __restrict__ z0g,
    const float* __restrict__ apg, const float* __restrict__ fbg,
    const float* __restrict__ dinv,
    float* __restrict__ x0, float* __restrict__ c0, float* __restrict__ y0, int N)
{
  __shared__ float z0s[NF][NC][DL];
  __shared__ float alps[NF][NC];
  __shared__ float bhs[NF][NC];
  __shared__ float lpc[NC];
  int tid = threadIdx.x;
  for (int i = tid; i < NF*NC*DL; i += 256)
    z0s[(i>>4)/NC][(i>>4)%NC][i&15] = z0g[i];
  if (tid < NF*NC){
    int l = tid/NC, c = tid%NC;
    float al = softplus_(apg[tid]);
    alps[l][c] = al;
    bhs[l][c]  = -al + softplus_(fbg[tid]);
  }
  if (tid < NC) lpc[tid] = __logf(pc[tid]);
  __syncthreads();

  int idx = blockIdx.x*256 + tid;
  int n = idx >> 4, c = idx & 15;
  if (n >= N) return;
  float dn = dinv[n];
  if (c >= NC){ x0[idx] = 0.f; c0[idx] = 0.f; y0[idx] = 0.f; return; }

  float zz[DL];
  const float4* z4 = (const float4*)z;
  #pragma unroll
  for (int q=0; q<4; ++q){
    float4 v = z4[(size_t)n*4 + q];
    zz[q*4+0]=v.x; zz[q*4+1]=v.y; zz[q*4+2]=v.z; zz[q*4+3]=v.w;
  }
  const float NEGHALFD_LOG2PI = -14.703016531274762f;  // -8*log(2*pi)
  const float LOGSCALE        =  20.248193975754326f;  //  8*log(4*pi)
  float sld = 0.f;
  #pragma unroll 1
  for (int l=0; l<NF; ++l){
    float al = alps[l][c], bhat = bhs[l][c];
    float dz[DL]; float r2 = 0.f;
    #pragma unroll
    for (int d=0; d<DL; ++d){ float t = zz[d] - z0s[l][c][d]; dz[d]=t; r2 = fmaf(t,t,r2); }
    float r  = sqrtf(r2);
    float hh = 1.0f/(al + r);
    float bh = bhat*hh;
    #pragma unroll
    for (int d=0; d<DL; ++d) zz[d] = fmaf(bh, dz[d], zz[d]);
    sld += 15.0f*__logf(1.0f + bh) + __logf(1.0f + bh - bhat*r*hh*hh);
  }
  float q2 = 0.f;
  #pragma unroll
  for (int d=0; d<DL; ++d) q2 = fmaf(zz[d], zz[d], q2);
  float v = -0.5f*q2 + NEGHALFD_LOG2PI + sld + lpc[c] + LOGSCALE;
  v = fminf(fmaxf(v, -30.f), 30.f);
  float xv = __expf(v);
  x0[idx] = xv;
  c0[idx] = dn*xv;
  y0[idx] = 0.1f*dn*xv;
}

// ---------------- bucketed CSR construction ----------------
__global__ __launch_bounds__(256) void k_bhist(const int* __restrict__ dst,
    int* __restrict__ bCnt, int E, int B)
{
  __shared__ int hh[MAXB];
  int tid = threadIdx.x;
  for (int b = tid; b < B; b += 256) hh[b] = 0;
  __syncthreads();
  for (int i = blockIdx.x*256 + tid; i < E; i += gridDim.x*256)
    atomicAdd(&hh[dst[i] >> BSH], 1);
  __syncthreads();
  for (int b = tid; b < B; b += 256) if (hh[b]) atomicAdd(&bCnt[b], hh[b]);
}

__global__ void k_bscan(const int* __restrict__ bCnt, int* __restrict__ bOff, int B){
  if (blockIdx.x==0 && threadIdx.x==0){
    int run = 0;
    for (int b=0;b<B;++b){ bOff[b]=run; run+=bCnt[b]; }
    bOff[B]=run;
  }
}

__global__ __launch_bounds__(256) void k_bscatter(const int* __restrict__ src,
    const int* __restrict__ dst, const int* __restrict__ bOff,
    int* __restrict__ bCur, int* __restrict__ bp, int E, int B)
{
  __shared__ int hc[MAXB];
  __shared__ int hb[MAXB];
  int tid = threadIdx.x;
  int base = blockIdx.x * TILE;
  int lim  = base + TILE; if (lim > E) lim = E;
  for (int b = tid; b < B; b += 256) hc[b] = 0;
  __syncthreads();
  for (int i = base + tid; i < lim; i += 256)
    atomicAdd(&hc[dst[i] >> BSH], 1);
  __syncthreads();
  for (int b = tid; b < B; b += 256){
    int c = hc[b];
    hb[b] = c ? atomicAdd(&bCur[b], c) : 0;
    hc[b] = 0;
  }
  __syncthreads();
  for (int i = base + tid; i < lim; i += 256){
    int d = dst[i];
    int b = d >> BSH;
    int pos = bOff[b] + hb[b] + atomicAdd(&hc[b], 1);
    bp[pos] = (src[i] << BSH) | (d & (BW-1));
  }
}

// per-bucket in-degree count (+1 self loop) fused with dinv/dinv2
__global__ __launch_bounds__(256) void k_bdeg(const int* __restrict__ bp,
    const int* __restrict__ bOff, int* __restrict__ deg,
    float* __restrict__ dinv, float* __restrict__ dinv2, int N)
{
  __shared__ int cur[BW];
  int tid = threadIdx.x;
  int b = blockIdx.x;
  if (tid < BW) cur[tid] = 0;
  __syncthreads();
  int s = bOff[b], e = bOff[b+1];
  for (int i = s + tid; i < e; i += 256)
    atomicAdd(&cur[bp[i] & (BW-1)], 1);
  __syncthreads();
  int node = (b << BSH) + tid;
  if (tid < BW && node < N){
    int d = cur[tid] + 1;                 // +1 self loop
    deg[node] = d;
    float dv = 1.0f / sqrtf((float)d);
    dinv[node]  = dv;
    dinv2[node] = dv*dv;
  }
}

__global__ __launch_bounds__(256) void k_scan_part(const int* __restrict__ deg,
    int* __restrict__ part, int N){
  __shared__ int sd[256];
  int base = blockIdx.x*1024;
  int tid = threadIdx.x;
  int s = 0;
  #pragma unroll
  for (int i=0;i<4;++i){ int idx = base + tid*4 + i; if (idx < N) s += deg[idx]; }
  sd[tid] = s; __syncthreads();
  for (int ofs=128; ofs>0; ofs>>=1){ if (tid<ofs) sd[tid]+=sd[tid+ofs]; __syncthreads(); }
  if (tid==0) part[blockIdx.x] = sd[0];
}

__global__ void k_scan_top(int* part, int nb){
  if (blockIdx.x==0 && threadIdx.x==0){
    int run = 0;
    for (int i=0;i<nb;++i){ int v = part[i]; part[i] = run; run += v; }
  }
}

__global__ __launch_bounds__(256) void k_scan_final(const int* __restrict__ deg,
    const int* __restrict__ part, int* __restrict__ off, int N, int E)
{
  __shared__ int sc[256];
  int base = blockIdx.x*1024;
  int tid = threadIdx.x;
  int v[4]; int s = 0;
  #pragma unroll
  for (int i=0;i<4;++i){ int idx = base + tid*4 + i; v[i] = (idx<N)?deg[idx]:0; s += v[i]; }
  sc[tid] = s; __syncthreads();
  for (int ofs=1; ofs<256; ofs<<=1){
    int t = (tid>=ofs) ? sc[tid-ofs] : 0;
    __syncthreads();
    sc[tid] += t;
    __syncthreads();
  }
  int ex = sc[tid] - s + part[blockIdx.x];
  #pragma unroll
  for (int i=0;i<4;++i){
    int idx = base + tid*4 + i;
    if (idx < N){
      off[idx] = ex;
      if (idx == N-1) off[N] = ex + v[i];
      ex += v[i];
    }
  }
}

// place self edge (slot 0) + src ints at CSR positions
__global__ __launch_bounds__(256) void k_place(const int* __restrict__ bp,
    const int* __restrict__ bOff, const int* __restrict__ off,
    int* __restrict__ csr, int N)
{
  __shared__ int cur[BW];
  int tid = threadIdx.x;
  int b = blockIdx.x;
  int node0 = b << BSH;
  if (tid < BW){
    cur[tid] = 1;                                 // slot 0 reserved for self
    int node = node0 + tid;
    if (node < N) csr[off[node]] = node;
  }
  __syncthreads();
  int s = bOff[b], e = bOff[b+1];
  for (int i = s + tid; i < e; i += 256){
    int v  = bp[i];
    int dl = v & (BW-1);
    int sn = v >> BSH;
    int d  = node0 + dl;
    int p  = off[d] + atomicAdd(&cur[dl], 1);
    csr[p] = sn;
  }
}

// ---- canonicalize segment order (stable value-rank via shuffles) ----
// Also emits per-node source-tile boundaries tb[n][t] = #edges with src <
// (t+1)*TS for t=0..6, tb[n][7] = degree (ushort, 16B/node).
__global__ __launch_bounds__(256) void k_rank(int* __restrict__ csr,
    const int* __restrict__ off, unsigned short* __restrict__ tb, int N)
{
  int wid  = (blockIdx.x*256 + threadIdx.x) >> 6;
  int lane = threadIdx.x & 63;
  if (wid >= N) return;
  int s = off[wid], e = off[wid+1];
  int d = e - s;
  if (d <= 0){
    if (lane < 8) tb[(size_t)wid*8 + lane] = 0;
    return;
  }
  if (d <= 64){
    int v = (lane < d) ? csr[s+lane] : INT_MAX;
    int rank = 0;
    for (int j = 0; j < d; ++j){
      int bv = __shfl(v, j);
      rank += (bv < v) || (bv == v && j < lane);
    }
    if (lane < d) csr[s+rank] = v;
    unsigned int myc = (unsigned)d;
    #pragma unroll
    for (int t = 0; t < 7; ++t){
      unsigned long long m = __ballot((lane < d) && (v < (t+1)*TS));
      if (lane == t) myc = (unsigned)__popcll(m);
    }
    if (lane < 8) tb[(size_t)wid*8 + lane] = (unsigned short)((lane < 7) ? myc : (unsigned)d);
  } else if (d <= 256){
    int v0 = (lane      < d) ? csr[s+lane      ] : INT_MAX;
    int v1 = (lane+64   < d) ? csr[s+lane+64   ] : INT_MAX;
    int v2 = (lane+128  < d) ? csr[s+lane+128  ] : INT_MAX;
    int v3 = (lane+192  < d) ? csr[s+lane+192  ] : INT_MAX;
    int r0=0,r1=0,r2=0,r3=0;
    for (int j = 0; j < d; ++j){
      int slot = j >> 6, jl = j & 63;
      int bv = (slot==0) ? __shfl(v0,jl) : (slot==1) ? __shfl(v1,jl)
             : (slot==2) ? __shfl(v2,jl) : __shfl(v3,jl);
      r0 += (bv < v0) || (bv == v0 && j < lane);
      r1 += (bv < v1) || (bv == v1 && j < lane+64);
      r2 += (bv < v2) || (bv == v2 && j < lane+128);
      r3 += (bv < v3) || (bv == v3 && j < lane+192);
    }
    if (lane      < d) csr[s+r0]=v0;
    if (lane+64   < d) csr[s+r1]=v1;
    if (lane+128  < d) csr[s+r2]=v2;
    if (lane+192  < d) csr[s+r3]=v3;
    unsigned int myc = (unsigned)d;
    #pragma unroll
    for (int t = 0; t < 7; ++t){
      int lim = (t+1)*TS;
      unsigned long long m0 = __ballot((lane      < d) && (v0 < lim));
      unsigned long long m1 = __ballot((lane+64   < d) && (v1 < lim));
      unsigned long long m2 = __ballot((lane+128  < d) && (v2 < lim));
      unsigned long long m3 = __ballot((lane+192  < d) && (v3 < lim));
      if (lane == t)
        myc = (unsigned)(__popcll(m0)+__popcll(m1)+__popcll(m2)+__popcll(m3));
    }
    if (lane < 8) tb[(size_t)wid*8 + lane] = (unsigned short)((lane < 7) ? myc : (unsigned)d);
  } else {
    if (lane == 0){
      for (int i = s+1; i < e; ++i){
        int key = csr[i]; int j = i-1;
        while (j >= s && csr[j] > key){ csr[j+1] = csr[j]; --j; }
        csr[j+1] = key;
      }
      for (int t = 0; t < 7; ++t){
        int lim = (t+1)*TS;
        int c = 0;
        for (int i = s; i < e; ++i) c += (csr[i] < lim);
        tb[(size_t)wid*8 + t] = (unsigned short)c;
      }
      tb[(size_t)wid*8 + 7] = (unsigned short)d;
    }
  }
}

// ---- APPNP c-space iteration, src-tiled + 2 accumulators, unroll 8 ----
// Tile t covers sources [t*TS,(t+1)*TS) = 1MB of c (L2-resident window);
// block barrier per tile bounds drift. Accumulation order fixed -> deterministic.
__global__ __launch_bounds__(256) void k_prop(const float* __restrict__ cin,
    const float* __restrict__ y0, const float* __restrict__ dinv2,
    float* __restrict__ cout, const int* __restrict__ csr,
    const int* __restrict__ off, const unsigned short* __restrict__ tb,
    int N, int NT)
{
  int t0 = blockIdx.x*256 + threadIdx.x;
  int n = t0 >> 2, q = t0 & 3;
  bool valid = (n < N);
  int nc = valid ? n : (N-1);
  const float4* c4 = (const float4*)cin;
  float4 a0 = make_float4(0.f,0.f,0.f,0.f);
  float4 a1 = make_float4(0.f,0.f,0.f,0.f);
  int s = off[nc], e = off[nc+1];
  uint4 bw = *(const uint4*)(tb + (size_t)nc*8);
  if (!valid) e = s;
  int i = s;
  #pragma unroll
  for (int t = 0; t < 8; ++t){
    if (t < NT){
      int lim;
      if (t == NT-1) lim = e;
      else {
        unsigned w = (t < 2) ? bw.x : (t < 4) ? bw.y : (t < 6) ? bw.z : bw.w;
        unsigned c = (t & 1) ? (w >> 16) : (w & 0xffffu);
        lim = s + (int)c;
        if (lim > e) lim = e;
      }
      for (; i+8 <= lim; i += 8){
        int s0=csr[i],   s1=csr[i+1], s2=csr[i+2], s3=csr[i+3];
        int s4=csr[i+4], s5=csr[i+5], s6=csr[i+6], s7=csr[i+7];
        float4 v0 = c4[(size_t)s0*4 + q];
        float4 v1 = c4[(size_t)s1*4 + q];
        float4 v2 = c4[(size_t)s2*4 + q];
        float4 v3 = c4[(size_t)s3*4 + q];
        float4 v4 = c4[(size_t)s4*4 + q];
        float4 v5 = c4[(size_t)s5*4 + q];
        float4 v6 = c4[(size_t)s6*4 + q];
        float4 v7 = c4[(size_t)s7*4 + q];
        a0.x+=v0.x; a0.y+=v0.y; a0.z+=v0.z; a0.w+=v0.w;
        a1.x+=v1.x; a1.y+=v1.y; a1.z+=v1.z; a1.w+=v1.w;
        a0.x+=v2.x; a0.y+=v2.y; a0.z+=v2.z; a0.w+=v2.w;
        a1.x+=v3.x; a1.y+=v3.y; a1.z+=v3.z; a1.w+=v3.w;
        a0.x+=v4.x; a0.y+=v4.y; a0.z+=v4.z; a0.w+=v4.w;
        a1.x+=v5.x; a1.y+=v5.y; a1.z+=v5.z; a1.w+=v5.w;
        a0.x+=v6.x; a0.y+=v6.y; a0.z+=v6.z; a0.w+=v6.w;
        a1.x+=v7.x; a1.y+=v7.y; a1.z+=v7.z; a1.w+=v7.w;
      }
      for (; i+2 <= lim; i += 2){
        int s0=csr[i], s1=csr[i+1];
        float4 v0 = c4[(size_t)s0*4 + q];
        float4 v1 = c4[(size_t)s1*4 + q];
        a0.x+=v0.x; a0.y+=v0.y; a0.z+=v0.z; a0.w+=v0.w;
        a1.x+=v1.x; a1.y+=v1.y; a1.z+=v1.z; a1.w+=v1.w;
      }
      if (i < lim){
        float4 v = c4[(size_t)csr[i]*4 + q];
        a0.x+=v.x; a0.y+=v.y; a0.z+=v.z; a0.w+=v.w;
        ++i;
      }
      __syncthreads();
    }
  }
  if (valid){
    float w9 = 0.9f * dinv2[n];
    float4 yv = ((const float4*)y0)[(size_t)n*4 + q];
    float4 o;
    o.x = fmaf(w9, a0.x+a1.x, yv.x);
    o.y = fmaf(w9, a0.y+a1.y, yv.y);
    o.z = fmaf(w9, a0.z+a1.z, yv.z);
    o.w = fmaf(w9, a0.w+a1.w, yv.w);
    ((float4*)cout)[(size_t)n*4 + q] = o;
  }
}

// ---- last iteration fused with alpha/soft/argmax (src-tiled too) ----
__global__ __launch_bounds__(256) void k_prop_final(const float* __restrict__ cin,
    const float* __restrict__ x0, const float* __restrict__ dinv,
    const int* __restrict__ csr, const int* __restrict__ off,
    const unsigned short* __restrict__ tb,
    float* __restrict__ out, int N, int NT)
{
  int t0 = blockIdx.x*256 + threadIdx.x;
  int n = t0 >> 2, q = t0 & 3;
  bool valid = (n < N);
  int nc = valid ? n : (N-1);
  const float4* c4 = (const float4*)cin;
  float4 a0 = make_float4(0.f,0.f,0.f,0.f);
  float4 a1 = make_float4(0.f,0.f,0.f,0.f);
  int s = off[nc], e = off[nc+1];
  uint4 bw = *(const uint4*)(tb + (size_t)nc*8);
  if (!valid) e = s;
  int i = s;
  #pragma unroll
  for (int t = 0; t < 8; ++t){
    if (t < NT){
      int lim;
      if (t == NT-1) lim = e;
      else {
        unsigned w = (t < 2) ? bw.x : (t < 4) ? bw.y : (t < 6) ? bw.z : bw.w;
        unsigned c = (t & 1) ? (w >> 16) : (w & 0xffffu);
        lim = s + (int)c;
        if (lim > e) lim = e;
      }
      for (; i+8 <= lim; i += 8){
        int s0=csr[i],   s1=csr[i+1], s2=csr[i+2], s3=csr[i+3];
        int s4=csr[i+4], s5=csr[i+5], s6=csr[i+6], s7=csr[i+7];
        float4 v0 = c4[(size_t)s0*4 + q];
        float4 v1 = c4[(size_t)s1*4 + q];
        float4 v2 = c4[(size_t)s2*4 + q];
        float4 v3 = c4[(size_t)s3*4 + q];
        float4 v4 = c4[(size_t)s4*4 + q];
        float4 v5 = c4[(size_t)s5*4 + q];
        float4 v6 = c4[(size_t)s6*4 + q];
        float4 v7 = c4[(size_t)s7*4 + q];
        a0.x+=v0.x; a0.y+=v0.y; a0.z+=v0.z; a0.w+=v0.w;
        a1.x+=v1.x; a1.y+=v1.y; a1.z+=v1.z; a1.w+=v1.w;
        a0.x+=v2.x; a0.y+=v2.y; a0.z+=v2.z; a0.w+=v2.w;
        a1.x+=v3.x; a1.y+=v3.y; a1.z+=v3.z; a1.w+=v3.w;
        a0.x+=v4.x; a0.y+=v4.y; a0.z+=v4.z; a0.w+=v4.w;
        a1.x+=v5.x; a1.y+=v5.y; a1.z+=v5.z; a1.w+=v5.w;
        a0.x+=v6.x; a0.y+=v6.y; a0.z+=v6.z; a0.w+=v6.w;
        a1.x+=v7.x; a1.y+=v7.y; a1.z+=v7.z; a1.w+=v7.w;
      }
      for (; i+2 <= lim; i += 2){
        int s0=csr[i], s1=csr[i+1];
        float4 v0 = c4[(size_t)s0*4 + q];
        float4 v1 = c4[(size_t)s1*4 + q];
        a0.x+=v0.x; a0.y+=v0.y; a0.z+=v0.z; a0.w+=v0.w;
        a1.x+=v1.x; a1.y+=v1.y; a1.z+=v1.z; a1.w+=v1.w;
      }
      if (i < lim){
        float4 v = c4[(size_t)csr[i]*4 + q];
        a0.x+=v.x; a0.y+=v.y; a0.z+=v.z; a0.w+=v.w;
        ++i;
      }
      __syncthreads();
    }
  }
  if (!valid) return;
  float w9 = 0.9f * dinv[n];
  float4 xv = ((const float4*)x0)[(size_t)n*4 + q];
  float4 al;
  al.x = fmaf(w9, a0.x+a1.x, fmaf(0.1f, xv.x, 1.f));
  al.y = fmaf(w9, a0.y+a1.y, fmaf(0.1f, xv.y, 1.f));
  al.z = fmaf(w9, a0.z+a1.z, fmaf(0.1f, xv.z, 1.f));
  al.w = fmaf(w9, a0.w+a1.w, fmaf(0.1f, xv.w, 1.f));

  float sv = 0.f;
  if (q < 2)       sv = al.x + al.y + al.z + al.w;
  else if (q == 2) sv = al.x + al.y;
  sv += __shfl_xor(sv, 1, 4);
  sv += __shfl_xor(sv, 2, 4);

  float bv = -1e30f; int bi = 999;
  int cb = q*4;
  int nvalid = (q < 2) ? 4 : (q == 2 ? 2 : 0);
  float av[4] = {al.x, al.y, al.z, al.w};
  for (int j = 0; j < nvalid; ++j){
    if (av[j] > bv){ bv = av[j]; bi = cb + j; }
  }
  #pragma unroll
  for (int o = 1; o <= 2; o <<= 1){
    float vo = __shfl_xor(bv, o, 4);
    int  io  = __shfl_xor(bi, o, 4);
    if (vo > bv || (vo == bv && io < bi)){ bv = vo; bi = io; }
  }

  float inv = 1.0f / sv;
  size_t sb = (size_t)N + (size_t)n*NC;
  for (int j = 0; j < nvalid; ++j) out[sb + cb + j] = av[j] * inv;
  if (q == 0) out[n] = (float)bi;
}

extern "C" void kernel_launch(void* const* d_in, const int* in_sizes, int n_in,
                              void* d_out, int out_size, void* d_ws, size_t ws_size,
                              hipStream_t stream)
{
  const float* x  = (const float*)d_in[0];
  const int*   ei = (const int*)  d_in[1];
  const float* pc = (const float*)d_in[2];
  const float* W1 = (const float*)d_in[3];
  const float* b1 = (const float*)d_in[4];
  const float* W2 = (const float*)d_in[5];
  const float* b2 = (const float*)d_in[6];
  const float* z0 = (const float*)d_in[7];
  const float* ap = (const float*)d_in[8];
  const float* fb = (const float*)d_in[9];
  float* out = (float*)d_out;

  const int N = in_sizes[0] / DF;
  const int E = in_sizes[1] / 2;
  const int* src = ei;
  const int* dst = ei + E;
  const int B = (N + BW - 1) >> BSH;
  const int NT = (N + TS - 1) / TS;     // source tiles (<=8 for N<=131072)

  // Workspace. region0 holds bp (E ints) during CSR build, then z (N*16 f32).
  char* ws = (char*)d_ws;
  size_t o = 0;
  size_t region0 = (size_t)E*sizeof(int);
  if ((size_t)N*DL*sizeof(float) > region0) region0 = (size_t)N*DL*sizeof(float);
  int*   bp   = (int*)  (ws + o);
  float* z    = (float*)(ws + o);
  o += region0;
  int*   csr  = (int*)  (ws + o); o += (size_t)(E+N)*sizeof(int);   // +N self edges
  float* x0   = (float*)(ws + o); o += (size_t)N*DL*sizeof(float);
  float* c0   = (float*)(ws + o); o += (size_t)N*DL*sizeof(float);
  float* y0   = (float*)(ws + o); o += (size_t)N*DL*sizeof(float);
  float* cA   = (float*)(ws + o); o += (size_t)N*DL*sizeof(float);
  float* cB   = (float*)(ws + o); o += (size_t)N*DL*sizeof(float);
  int*   deg  = (int*)  (ws + o); o += (size_t)N*sizeof(int);
  float* dinv = (float*)(ws + o); o += (size_t)N*sizeof(float);
  float* dinv2= (float*)(ws + o); o += (size_t)N*sizeof(float);
  unsigned short* tb = (unsigned short*)(ws + o); o += (size_t)N*8*sizeof(unsigned short);
  int*   offs = (int*)  (ws + o); o += (size_t)(N+2)*sizeof(int);
  int*   part = (int*)  (ws + o); o += 4096;
  int*   bCnt = (int*)  (ws + o); o += MAXB*sizeof(int);
  int*   bOff = (int*)  (ws + o); o += (MAXB+1)*sizeof(int);
  int*   bCur = (int*)  (ws + o); o += MAXB*sizeof(int);

  const int TB = 256;
  int nb  = (N + 1023) / 1024;

  // Phase 1: bucketed CSR build (bp lives in region0)
  hipMemsetAsync(bCnt, 0, MAXB*sizeof(int), stream);
  hipMemsetAsync(bCur, 0, MAXB*sizeof(int), stream);
  k_bhist<<<512, TB, 0, stream>>>(dst, bCnt, E, B);
  k_bscan<<<1, 1, 0, stream>>>(bCnt, bOff, B);
  k_bscatter<<<(E + TILE - 1)/TILE, TB, 0, stream>>>(src, dst, bOff, bCur, bp, E, B);
  k_bdeg<<<B, TB, 0, stream>>>(bp, bOff, deg, dinv, dinv2, N);
  k_scan_part<<<nb, TB, 0, stream>>>(deg, part, N);
  k_scan_top<<<1, 1, 0, stream>>>(part, nb);
  k_scan_final<<<nb, TB, 0, stream>>>(deg, part, offs, N, E);
  k_place<<<B, TB, 0, stream>>>(bp, bOff, offs, csr, N);
  k_rank<<<(N + 3) / 4, TB, 0, stream>>>(csr, offs, tb, N);

  // Phase 2: encoder fused with z projection (z overwrites bp), then flows
  k_gemm1z<<<(N + BM - 1) / BM, TB, 0, stream>>>(x, W1, b1, W2, b2, z, N);
  k_flow2<<<((N*DL) + TB - 1) / TB, TB, 0, stream>>>(z, pc, z0, ap, fb, dinv,
                                                     x0, c0, y0, N);

  // Phase 3: APPNP in c-space — 9 tiled iterations + 1 fused with epilogue
  int gP = ((N*4) + TB - 1) / TB;
  const float* cin = c0;
  for (int it = 0; it < KPROP-1; ++it){
    float* cout = (it & 1) ? cB : cA;
    k_prop<<<gP, TB, 0, stream>>>(cin, y0, dinv2, cout, csr, offs, tb, N, NT);
    cin = cout;
  }
  k_prop_final<<<gP, TB, 0, stream>>>(cin, x0, dinv, csr, offs, tb, out, N, NT);
}

// Round 12
// 772.848 us; speedup vs baseline: 1.1909x; 1.0160x over previous
//
#include <hip/hip_runtime.h>
#include <math.h>
#include <limits.h>

#define DF 512
#define DH 64
#define DL 16
#define NC 10
#define NF 10
#define KPROP 10

#define BSH 7                  // bucket shift: 128 nodes per bucket
#define BW  (1 << BSH)
#define MAXB 1024
#define TILE 16384

__device__ __forceinline__ float softplus_(float x){
  return fmaxf(x, 0.0f) + log1pf(expf(-fabsf(x)));
}

// -------- GEMM1 fused with z-projection: z = relu(x@W1+b1) @ W2 + b2 --------
// (proven config: 64x64 tile, 4x4 microtile, BK=32, 124us, 36 VGPR — FINAL)
#define BM 64
#define BN 64
#define BK 32
__global__ __launch_bounds__(256) void k_gemm1z(const float* __restrict__ x,
    const float* __restrict__ W1, const float* __restrict__ b1,
    const float* __restrict__ W2, const float* __restrict__ b2,
    float* __restrict__ z, int N)
{
  __shared__ float smem[2*BK*(BM+4)];           // At | Bs, later overlaid by hs[64][68]
  float (*At)[BM+4] = (float(*)[BM+4])smem;
  float (*Bs)[BN+4] = (float(*)[BN+4])(smem + BK*(BM+4));
  __shared__ float W2s[DH][DL];
  __shared__ float b2s[DL];
  const int tid = threadIdx.x;
  for (int i = tid; i < DH*DL; i += 256) W2s[i>>4][i&15] = W2[i];
  if (tid < DL) b2s[tid] = b2[tid];
  const int tx = tid & 15, ty = tid >> 4;
  const int row0 = blockIdx.x * BM;
  float acc[4][4] = {};
  for (int k0 = 0; k0 < DF; k0 += BK) {
    #pragma unroll
    for (int i = 0; i < 2; ++i) {
      int idx = tid + i*256;
      int r  = idx >> 3;
      int kk = (idx & 7) << 2;
      int row = row0 + r;
      float4 va = make_float4(0.f,0.f,0.f,0.f);
      if (row < N) va = *(const float4*)&x[(size_t)row*DF + k0 + kk];
      At[kk+0][r]=va.x; At[kk+1][r]=va.y; At[kk+2][r]=va.z; At[kk+3][r]=va.w;
      int r2 = idx >> 4;
      int c4 = (idx & 15) << 2;
      float4 vb = *(const float4*)&W1[(size_t)(k0+r2)*DH + c4];
      Bs[r2][c4+0]=vb.x; Bs[r2][c4+1]=vb.y; Bs[r2][c4+2]=vb.z; Bs[r2][c4+3]=vb.w;
    }
    __syncthreads();
    #pragma unroll
    for (int kk = 0; kk < BK; ++kk) {
      float4 av = *(const float4*)&At[kk][ty<<2];
      float4 bv = *(const float4*)&Bs[kk][tx<<2];
      float a4[4]={av.x,av.y,av.z,av.w};
      float b4[4]={bv.x,bv.y,bv.z,bv.w};
      #pragma unroll
      for (int i=0;i<4;++i)
        #pragma unroll
        for (int j=0;j<4;++j) acc[i][j] = fmaf(a4[i], b4[j], acc[i][j]);
    }
    __syncthreads();
  }
  // epilogue: h tile -> LDS (overlay), then z = h@W2+b2
  float4 bias = ((const float4*)b1)[tx];
  float bias4[4] = {bias.x, bias.y, bias.z, bias.w};
  float (*hs)[BM+4] = (float(*)[BM+4])smem;
  #pragma unroll
  for (int i=0;i<4;++i){
    #pragma unroll
    for (int j=0;j<4;++j)
      hs[(ty<<2)+i][(tx<<2)+j] = fmaxf(acc[i][j] + bias4[j], 0.0f);
  }
  __syncthreads();
  int row = tid >> 2, lg = tid & 3;
  float4 zacc = ((const float4*)b2s)[lg];
  #pragma unroll 8
  for (int k = 0; k < DH; ++k){
    float hv = hs[row][k];
    float4 wv = *(const float4*)&W2s[k][lg<<2];
    zacc.x = fmaf(hv, wv.x, zacc.x);
    zacc.y = fmaf(hv, wv.y, zacc.y);
    zacc.z = fmaf(hv, wv.z, zacc.z);
    zacc.w = fmaf(hv, wv.w, zacc.w);
  }
  int grow = row0 + row;
  if (grow < N) ((float4*)z)[(size_t)grow*4 + lg] = zacc;
}

// -------- radial flows: one thread per (node, class) --------
__global__ __launch_bounds__(256) void k_flow2(const float* __restrict__ z,
    const float* __restrict__ pc, const float* __restrict__ z0g,
    const float* __restrict__ apg, const float* __restrict__ fbg,
    const float* __restrict__ dinv,
    float* __restrict__ x0, float* __restrict__ c0, float* __restrict__ y0, int N)
{
  __shared__ float z0s[NF][NC][DL];
  __shared__ float alps[NF][NC];
  __shared__ float bhs[NF][NC];
  __shared__ float lpc[NC];
  int tid = threadIdx.x;
  for (int i = tid; i < NF*NC*DL; i += 256)
    z0s[(i>>4)/NC][(i>>4)%NC][i&15] = z0g[i];
  if (tid < NF*NC){
    int l = tid/NC, c = tid%NC;
    float al = softplus_(apg[tid]);
    alps[l][c] = al;
    bhs[l][c]  = -al + softplus_(fbg[tid]);
  }
  if (tid < NC) lpc[tid] = __logf(pc[tid]);
  __syncthreads();

  int idx = blockIdx.x*256 + tid;
  int n = idx >> 4, c = idx & 15;
  if (n >= N) return;
  float dn = dinv[n];
  if (c >= NC){ x0[idx] = 0.f; c0[idx] = 0.f; y0[idx] = 0.f; return; }

  float zz[DL];
  const float4* z4 = (const float4*)z;
  #pragma unroll
  for (int q=0; q<4; ++q){
    float4 v = z4[(size_t)n*4 + q];
    zz[q*4+0]=v.x; zz[q*4+1]=v.y; zz[q*4+2]=v.z; zz[q*4+3]=v.w;
  }
  const float NEGHALFD_LOG2PI = -14.703016531274762f;  // -8*log(2*pi)
  const float LOGSCALE        =  20.248193975754326f;  //  8*log(4*pi)
  float sld = 0.f;
  #pragma unroll 1
  for (int l=0; l<NF; ++l){
    float al = alps[l][c], bhat = bhs[l][c];
    float dz[DL]; float r2 = 0.f;
    #pragma unroll
    for (int d=0; d<DL; ++d){ float t = zz[d] - z0s[l][c][d]; dz[d]=t; r2 = fmaf(t,t,r2); }
    float r  = sqrtf(r2);
    float hh = 1.0f/(al + r);
    float bh = bhat*hh;
    #pragma unroll
    for (int d=0; d<DL; ++d) zz[d] = fmaf(bh, dz[d], zz[d]);
    sld += 15.0f*__logf(1.0f + bh) + __logf(1.0f + bh - bhat*r*hh*hh);
  }
  float q2 = 0.f;
  #pragma unroll
  for (int d=0; d<DL; ++d) q2 = fmaf(zz[d], zz[d], q2);
  float v = -0.5f*q2 + NEGHALFD_LOG2PI + sld + lpc[c] + LOGSCALE;
  v = fminf(fmaxf(v, -30.f), 30.f);
  float xv = __expf(v);
  x0[idx] = xv;
  c0[idx] = dn*xv;
  y0[idx] = 0.1f*dn*xv;
}

// ---------------- bucketed CSR construction ----------------
__global__ __launch_bounds__(256) void k_bhist(const int* __restrict__ dst,
    int* __restrict__ bCnt, int E, int B)
{
  __shared__ int hh[MAXB];
  int tid = threadIdx.x;
  for (int b = tid; b < B; b += 256) hh[b] = 0;
  __syncthreads();
  for (int i = blockIdx.x*256 + tid; i < E; i += gridDim.x*256)
    atomicAdd(&hh[dst[i] >> BSH], 1);
  __syncthreads();
  for (int b = tid; b < B; b += 256) if (hh[b]) atomicAdd(&bCnt[b], hh[b]);
}

__global__ void k_bscan(const int* __restrict__ bCnt, int* __restrict__ bOff, int B){
  if (blockIdx.x==0 && threadIdx.x==0){
    int run = 0;
    for (int b=0;b<B;++b){ bOff[b]=run; run+=bCnt[b]; }
    bOff[B]=run;
  }
}

__global__ __launch_bounds__(256) void k_bscatter(const int* __restrict__ src,
    const int* __restrict__ dst, const int* __restrict__ bOff,
    int* __restrict__ bCur, int* __restrict__ bp, int E, int B)
{
  __shared__ int hc[MAXB];
  __shared__ int hb[MAXB];
  int tid = threadIdx.x;
  int base = blockIdx.x * TILE;
  int lim  = base + TILE; if (lim > E) lim = E;
  for (int b = tid; b < B; b += 256) hc[b] = 0;
  __syncthreads();
  for (int i = base + tid; i < lim; i += 256)
    atomicAdd(&hc[dst[i] >> BSH], 1);
  __syncthreads();
  for (int b = tid; b < B; b += 256){
    int c = hc[b];
    hb[b] = c ? atomicAdd(&bCur[b], c) : 0;
    hc[b] = 0;
  }
  __syncthreads();
  for (int i = base + tid; i < lim; i += 256){
    int d = dst[i];
    int b = d >> BSH;
    int pos = bOff[b] + hb[b] + atomicAdd(&hc[b], 1);
    bp[pos] = (src[i] << BSH) | (d & (BW-1));
  }
}

// per-bucket in-degree count (+1 self loop) fused with dinv/dinv2
__global__ __launch_bounds__(256) void k_bdeg(const int* __restrict__ bp,
    const int* __restrict__ bOff, int* __restrict__ deg,
    float* __restrict__ dinv, float* __restrict__ dinv2, int N)
{
  __shared__ int cur[BW];
  int tid = threadIdx.x;
  int b = blockIdx.x;
  if (tid < BW) cur[tid] = 0;
  __syncthreads();
  int s = bOff[b], e = bOff[b+1];
  for (int i = s + tid; i < e; i += 256)
    atomicAdd(&cur[bp[i] & (BW-1)], 1);
  __syncthreads();
  int node = (b << BSH) + tid;
  if (tid < BW && node < N){
    int d = cur[tid] + 1;                 // +1 self loop
    deg[node] = d;
    float dv = 1.0f / sqrtf((float)d);
    dinv[node]  = dv;
    dinv2[node] = dv*dv;
  }
}

__global__ __launch_bounds__(256) void k_scan_part(const int* __restrict__ deg,
    int* __restrict__ part, int N){
  __shared__ int sd[256];
  int base = blockIdx.x*1024;
  int tid = threadIdx.x;
  int s = 0;
  #pragma unroll
  for (int i=0;i<4;++i){ int idx = base + tid*4 + i; if (idx < N) s += deg[idx]; }
  sd[tid] = s; __syncthreads();
  for (int ofs=128; ofs>0; ofs>>=1){ if (tid<ofs) sd[tid]+=sd[tid+ofs]; __syncthreads(); }
  if (tid==0) part[blockIdx.x] = sd[0];
}

__global__ void k_scan_top(int* part, int nb){
  if (blockIdx.x==0 && threadIdx.x==0){
    int run = 0;
    for (int i=0;i<nb;++i){ int v = part[i]; part[i] = run; run += v; }
  }
}

__global__ __launch_bounds__(256) void k_scan_final(const int* __restrict__ deg,
    const int* __restrict__ part, int* __restrict__ off, int N, int E)
{
  __shared__ int sc[256];
  int base = blockIdx.x*1024;
  int tid = threadIdx.x;
  int v[4]; int s = 0;
  #pragma unroll
  for (int i=0;i<4;++i){ int idx = base + tid*4 + i; v[i] = (idx<N)?deg[idx]:0; s += v[i]; }
  sc[tid] = s; __syncthreads();
  for (int ofs=1; ofs<256; ofs<<=1){
    int t = (tid>=ofs) ? sc[tid-ofs] : 0;
    __syncthreads();
    sc[tid] += t;
    __syncthreads();
  }
  int ex = sc[tid] - s + part[blockIdx.x];
  #pragma unroll
  for (int i=0;i<4;++i){
    int idx = base + tid*4 + i;
    if (idx < N){
      off[idx] = ex;
      if (idx == N-1) off[N] = ex + v[i];
      ex += v[i];
    }
  }
}

// place self edge (slot 0) + src ints at CSR positions
__global__ __launch_bounds__(256) void k_place(const int* __restrict__ bp,
    const int* __restrict__ bOff, const int* __restrict__ off,
    int* __restrict__ csr, int N)
{
  __shared__ int cur[BW];
  int tid = threadIdx.x;
  int b = blockIdx.x;
  int node0 = b << BSH;
  if (tid < BW){
    cur[tid] = 1;                                 // slot 0 reserved for self
    int node = node0 + tid;
    if (node < N) csr[off[node]] = node;
  }
  __syncthreads();
  int s = bOff[b], e = bOff[b+1];
  for (int i = s + tid; i < e; i += 256){
    int v  = bp[i];
    int dl = v & (BW-1);
    int sn = v >> BSH;
    int d  = node0 + dl;
    int p  = off[d] + atomicAdd(&cur[dl], 1);
    csr[p] = sn;
  }
}

// ---- canonicalize segment order (stable value-rank via shuffles) ----
__global__ __launch_bounds__(256) void k_rank(int* __restrict__ csr,
    const int* __restrict__ off, int N)
{
  int wid  = (blockIdx.x*256 + threadIdx.x) >> 6;
  int lane = threadIdx.x & 63;
  if (wid >= N) return;
  int s = off[wid], e = off[wid+1];
  int d = e - s;
  if (d <= 1) return;
  if (d <= 64){
    int v = (lane < d) ? csr[s+lane] : INT_MAX;
    int rank = 0;
    for (int j = 0; j < d; ++j){
      int bv = __shfl(v, j);
      rank += (bv < v) || (bv == v && j < lane);
    }
    if (lane < d) csr[s+rank] = v;
  } else if (d <= 256){
    int v0 = (lane      < d) ? csr[s+lane      ] : INT_MAX;
    int v1 = (lane+64   < d) ? csr[s+lane+64   ] : INT_MAX;
    int v2 = (lane+128  < d) ? csr[s+lane+128  ] : INT_MAX;
    int v3 = (lane+192  < d) ? csr[s+lane+192  ] : INT_MAX;
    int r0=0,r1=0,r2=0,r3=0;
    for (int j = 0; j < d; ++j){
      int slot = j >> 6, jl = j & 63;
      int bv = (slot==0) ? __shfl(v0,jl) : (slot==1) ? __shfl(v1,jl)
             : (slot==2) ? __shfl(v2,jl) : __shfl(v3,jl);
      r0 += (bv < v0) || (bv == v0 && j < lane);
      r1 += (bv < v1) || (bv == v1 && j < lane+64);
      r2 += (bv < v2) || (bv == v2 && j < lane+128);
      r3 += (bv < v3) || (bv == v3 && j < lane+192);
    }
    if (lane      < d) csr[s+r0]=v0;
    if (lane+64   < d) csr[s+r1]=v1;
    if (lane+128  < d) csr[s+r2]=v2;
    if (lane+192  < d) csr[s+r3]=v3;
  } else {
    if (lane == 0){
      for (int i = s+1; i < e; ++i){
        int key = csr[i]; int j = i-1;
        while (j >= s && csr[j] > key){ csr[j+1] = csr[j]; --j; }
        csr[j+1] = key;
      }
    }
  }
}

// ---- APPNP c-space iteration: 16 threads/node (4 class-quads x 4 edge-quarters)
// Each thread gathers ~deg/4 edges -> 4x memory-level parallelism vs 4 thr/node.
// Deterministic: sorted csr, fixed integer quarter bounds, fixed combine order.
__global__ __launch_bounds__(256) void k_prop(const float* __restrict__ cin,
    const float* __restrict__ y0, const float* __restrict__ dinv2,
    float* __restrict__ cout,
    const int* __restrict__ csr, const int* __restrict__ off, int N)
{
  int t = blockIdx.x*256 + threadIdx.x;
  int n = t >> 4, sub = t & 15, q = sub & 3, part = sub >> 2;
  if (n >= N) return;
  const float4* c4 = (const float4*)cin;
  int s = off[n], e = off[n+1], d = e - s;
  int lo = s + ((d*part) >> 2);
  int hi = s + ((d*(part+1)) >> 2);
  float4 a0 = make_float4(0.f,0.f,0.f,0.f);
  float4 a1 = make_float4(0.f,0.f,0.f,0.f);
  int i = lo;
  for (; i+4 <= hi; i += 4){
    int s0=csr[i], s1=csr[i+1], s2=csr[i+2], s3=csr[i+3];
    float4 v0 = c4[(size_t)s0*4 + q];
    float4 v1 = c4[(size_t)s1*4 + q];
    float4 v2 = c4[(size_t)s2*4 + q];
    float4 v3 = c4[(size_t)s3*4 + q];
    a0.x+=v0.x; a0.y+=v0.y; a0.z+=v0.z; a0.w+=v0.w;
    a1.x+=v1.x; a1.y+=v1.y; a1.z+=v1.z; a1.w+=v1.w;
    a0.x+=v2.x; a0.y+=v2.y; a0.z+=v2.z; a0.w+=v2.w;
    a1.x+=v3.x; a1.y+=v3.y; a1.z+=v3.z; a1.w+=v3.w;
  }
  for (; i < hi; ++i){
    float4 v = c4[(size_t)csr[i]*4 + q];
    a0.x+=v.x; a0.y+=v.y; a0.z+=v.z; a0.w+=v.w;
  }
  float ax = a0.x+a1.x, ay = a0.y+a1.y, az = a0.z+a1.z, aw = a0.w+a1.w;
  ax += __shfl_xor(ax, 4, 16);  ay += __shfl_xor(ay, 4, 16);
  az += __shfl_xor(az, 4, 16);  aw += __shfl_xor(aw, 4, 16);
  ax += __shfl_xor(ax, 8, 16);  ay += __shfl_xor(ay, 8, 16);
  az += __shfl_xor(az, 8, 16);  aw += __shfl_xor(aw, 8, 16);
  if (part == 0){
    float w9 = 0.9f * dinv2[n];
    float4 yv = ((const float4*)y0)[(size_t)n*4 + q];
    float4 o;
    o.x = fmaf(w9, ax, yv.x);
    o.y = fmaf(w9, ay, yv.y);
    o.z = fmaf(w9, az, yv.z);
    o.w = fmaf(w9, aw, yv.w);
    ((float4*)cout)[(size_t)n*4 + q] = o;
  }
}

// ---- last iteration fused with alpha/soft/argmax (16 threads/node) ----
__global__ __launch_bounds__(256) void k_prop_final(const float* __restrict__ cin,
    const float* __restrict__ x0, const float* __restrict__ dinv,
    const int* __restrict__ csr, const int* __restrict__ off,
    float* __restrict__ out, int N)
{
  int t = blockIdx.x*256 + threadIdx.x;
  int n = t >> 4, sub = t & 15, q = sub & 3, part = sub >> 2;
  if (n >= N) return;
  const float4* c4 = (const float4*)cin;
  int s = off[n], e = off[n+1], d = e - s;
  int lo = s + ((d*part) >> 2);
  int hi = s + ((d*(part+1)) >> 2);
  float4 a0 = make_float4(0.f,0.f,0.f,0.f);
  float4 a1 = make_float4(0.f,0.f,0.f,0.f);
  int i = lo;
  for (; i+4 <= hi; i += 4){
    int s0=csr[i], s1=csr[i+1], s2=csr[i+2], s3=csr[i+3];
    float4 v0 = c4[(size_t)s0*4 + q];
    float4 v1 = c4[(size_t)s1*4 + q];
    float4 v2 = c4[(size_t)s2*4 + q];
    float4 v3 = c4[(size_t)s3*4 + q];
    a0.x+=v0.x; a0.y+=v0.y; a0.z+=v0.z; a0.w+=v0.w;
    a1.x+=v1.x; a1.y+=v1.y; a1.z+=v1.z; a1.w+=v1.w;
    a0.x+=v2.x; a0.y+=v2.y; a0.z+=v2.z; a0.w+=v2.w;
    a1.x+=v3.x; a1.y+=v3.y; a1.z+=v3.z; a1.w+=v3.w;
  }
  for (; i < hi; ++i){
    float4 v = c4[(size_t)csr[i]*4 + q];
    a0.x+=v.x; a0.y+=v.y; a0.z+=v.z; a0.w+=v.w;
  }
  float ax = a0.x+a1.x, ay = a0.y+a1.y, az = a0.z+a1.z, aw = a0.w+a1.w;
  ax += __shfl_xor(ax, 4, 16);  ay += __shfl_xor(ay, 4, 16);
  az += __shfl_xor(az, 4, 16);  aw += __shfl_xor(aw, 4, 16);
  ax += __shfl_xor(ax, 8, 16);  ay += __shfl_xor(ay, 8, 16);
  az += __shfl_xor(az, 8, 16);  aw += __shfl_xor(aw, 8, 16);
  if (part != 0) return;

  float w9 = 0.9f * dinv[n];
  float4 xv = ((const float4*)x0)[(size_t)n*4 + q];
  float4 al;
  al.x = fmaf(w9, ax, fmaf(0.1f, xv.x, 1.f));
  al.y = fmaf(w9, ay, fmaf(0.1f, xv.y, 1.f));
  al.z = fmaf(w9, az, fmaf(0.1f, xv.z, 1.f));
  al.w = fmaf(w9, aw, fmaf(0.1f, xv.w, 1.f));

  // lanes q=0..3 of this node (4-aligned within the wave): sum + argmax
  float sv = 0.f;
  if (q < 2)       sv = al.x + al.y + al.z + al.w;
  else if (q == 2) sv = al.x + al.y;
  sv += __shfl_xor(sv, 1, 4);
  sv += __shfl_xor(sv, 2, 4);

  float bv = -1e30f; int bi = 999;
  int cb = q*4;
  int nvalid = (q < 2) ? 4 : (q == 2 ? 2 : 0);
  float av[4] = {al.x, al.y, al.z, al.w};
  for (int j = 0; j < nvalid; ++j){
    if (av[j] > bv){ bv = av[j]; bi = cb + j; }
  }
  #pragma unroll
  for (int o = 1; o <= 2; o <<= 1){
    float vo = __shfl_xor(bv, o, 4);
    int  io  = __shfl_xor(bi, o, 4);
    if (vo > bv || (vo == bv && io < bi)){ bv = vo; bi = io; }
  }

  float inv = 1.0f / sv;
  size_t sb = (size_t)N + (size_t)n*NC;
  for (int j = 0; j < nvalid; ++j) out[sb + cb + j] = av[j] * inv;
  if (q == 0) out[n] = (float)bi;
}

extern "C" void kernel_launch(void* const* d_in, const int* in_sizes, int n_in,
                              void* d_out, int out_size, void* d_ws, size_t ws_size,
                              hipStream_t stream)
{
  const float* x  = (const float*)d_in[0];
  const int*   ei = (const int*)  d_in[1];
  const float* pc = (const float*)d_in[2];
  const float* W1 = (const float*)d_in[3];
  const float* b1 = (const float*)d_in[4];
  const float* W2 = (const float*)d_in[5];
  const float* b2 = (const float*)d_in[6];
  const float* z0 = (const float*)d_in[7];
  const float* ap = (const float*)d_in[8];
  const float* fb = (const float*)d_in[9];
  float* out = (float*)d_out;

  const int N = in_sizes[0] / DF;
  const int E = in_sizes[1] / 2;
  const int* src = ei;
  const int* dst = ei + E;
  const int B = (N + BW - 1) >> BSH;

  // Workspace. region0 holds bp (E ints) during CSR build, then z (N*16 f32).
  char* ws = (char*)d_ws;
  size_t o = 0;
  size_t region0 = (size_t)E*sizeof(int);
  if ((size_t)N*DL*sizeof(float) > region0) region0 = (size_t)N*DL*sizeof(float);
  int*   bp   = (int*)  (ws + o);
  float* z    = (float*)(ws + o);
  o += region0;
  int*   csr  = (int*)  (ws + o); o += (size_t)(E+N)*sizeof(int);   // +N self edges
  float* x0   = (float*)(ws + o); o += (size_t)N*DL*sizeof(float);
  float* c0   = (float*)(ws + o); o += (size_t)N*DL*sizeof(float);
  float* y0   = (float*)(ws + o); o += (size_t)N*DL*sizeof(float);
  float* cA   = (float*)(ws + o); o += (size_t)N*DL*sizeof(float);
  float* cB   = (float*)(ws + o); o += (size_t)N*DL*sizeof(float);
  int*   deg  = (int*)  (ws + o); o += (size_t)N*sizeof(int);
  float* dinv = (float*)(ws + o); o += (size_t)N*sizeof(float);
  float* dinv2= (float*)(ws + o); o += (size_t)N*sizeof(float);
  int*   offs = (int*)  (ws + o); o += (size_t)(N+2)*sizeof(int);
  int*   part = (int*)  (ws + o); o += 4096;
  int*   bCnt = (int*)  (ws + o); o += MAXB*sizeof(int);
  int*   bOff = (int*)  (ws + o); o += (MAXB+1)*sizeof(int);
  int*   bCur = (int*)  (ws + o); o += MAXB*sizeof(int);

  const int TB = 256;
  int nb  = (N + 1023) / 1024;

  // Phase 1: bucketed CSR build (bp lives in region0)
  hipMemsetAsync(bCnt, 0, MAXB*sizeof(int), stream);
  hipMemsetAsync(bCur, 0, MAXB*sizeof(int), stream);
  k_bhist<<<512, TB, 0, stream>>>(dst, bCnt, E, B);
  k_bscan<<<1, 1, 0, stream>>>(bCnt, bOff, B);
  k_bscatter<<<(E + TILE - 1)/TILE, TB, 0, stream>>>(src, dst, bOff, bCur, bp, E, B);
  k_bdeg<<<B, TB, 0, stream>>>(bp, bOff, deg, dinv, dinv2, N);
  k_scan_part<<<nb, TB, 0, stream>>>(deg, part, N);
  k_scan_top<<<1, 1, 0, stream>>>(part, nb);
  k_scan_final<<<nb, TB, 0, stream>>>(deg, part, offs, N, E);
  k_place<<<B, TB, 0, stream>>>(bp, bOff, offs, csr, N);
  k_rank<<<(N + 3) / 4, TB, 0, stream>>>(csr, offs, N);

  // Phase 2: encoder fused with z projection (z overwrites bp), then flows
  k_gemm1z<<<(N + BM - 1) / BM, TB, 0, stream>>>(x, W1, b1, W2, b2, z, N);
  k_flow2<<<((N*DL) + TB - 1) / TB, TB, 0, stream>>>(z, pc, z0, ap, fb, dinv,
                                                     x0, c0, y0, N);

  // Phase 3: APPNP in c-space — 9 iterations + 1 fused, 16 threads/node
  int gP = ((N*16) + TB - 1) / TB;
  const float* cin = c0;
  for (int it = 0; it < KPROP-1; ++it){
    float* cout = (it & 1) ? cB : cA;
    k_prop<<<gP, TB, 0, stream>>>(cin, y0, dinv2, cout, csr, offs, N);
    cin = cout;
  }
  k_prop_final<<<gP, TB, 0, stream>>>(cin, x0, dinv, csr, offs, out, N);
}

// Round 13
// 741.775 us; speedup vs baseline: 1.2408x; 1.0419x over previous
//
#include <hip/hip_runtime.h>
#include <math.h>
#include <limits.h>

#define DF 512
#define DH 64
#define DL 16
#define NC 10
#define NF 10
#define KPROP 10

#define BSH 7                  // bucket shift: 128 nodes per bucket
#define BW  (1 << BSH)
#define MAXB 1024
#define TILE 16384

__device__ __forceinline__ float softplus_(float x){
  return fmaxf(x, 0.0f) + log1pf(expf(-fabsf(x)));
}

// -------- GEMM1 fused with z-projection: z = relu(x@W1+b1) @ W2 + b2 --------
// (proven config: 64x64 tile, 4x4 microtile, BK=32, 124us, 36 VGPR — FINAL)
#define BM 64
#define BN 64
#define BK 32
__global__ __launch_bounds__(256) void k_gemm1z(const float* __restrict__ x,
    const float* __restrict__ W1, const float* __restrict__ b1,
    const float* __restrict__ W2, const float* __restrict__ b2,
    float* __restrict__ z, int N)
{
  __shared__ float smem[2*BK*(BM+4)];           // At | Bs, later overlaid by hs[64][68]
  float (*At)[BM+4] = (float(*)[BM+4])smem;
  float (*Bs)[BN+4] = (float(*)[BN+4])(smem + BK*(BM+4));
  __shared__ float W2s[DH][DL];
  __shared__ float b2s[DL];
  const int tid = threadIdx.x;
  for (int i = tid; i < DH*DL; i += 256) W2s[i>>4][i&15] = W2[i];
  if (tid < DL) b2s[tid] = b2[tid];
  const int tx = tid & 15, ty = tid >> 4;
  const int row0 = blockIdx.x * BM;
  float acc[4][4] = {};
  for (int k0 = 0; k0 < DF; k0 += BK) {
    #pragma unroll
    for (int i = 0; i < 2; ++i) {
      int idx = tid + i*256;
      int r  = idx >> 3;
      int kk = (idx & 7) << 2;
      int row = row0 + r;
      float4 va = make_float4(0.f,0.f,0.f,0.f);
      if (row < N) va = *(const float4*)&x[(size_t)row*DF + k0 + kk];
      At[kk+0][r]=va.x; At[kk+1][r]=va.y; At[kk+2][r]=va.z; At[kk+3][r]=va.w;
      int r2 = idx >> 4;
      int c4 = (idx & 15) << 2;
      float4 vb = *(const float4*)&W1[(size_t)(k0+r2)*DH + c4];
      Bs[r2][c4+0]=vb.x; Bs[r2][c4+1]=vb.y; Bs[r2][c4+2]=vb.z; Bs[r2][c4+3]=vb.w;
    }
    __syncthreads();
    #pragma unroll
    for (int kk = 0; kk < BK; ++kk) {
      float4 av = *(const float4*)&At[kk][ty<<2];
      float4 bv = *(const float4*)&Bs[kk][tx<<2];
      float a4[4]={av.x,av.y,av.z,av.w};
      float b4[4]={bv.x,bv.y,bv.z,bv.w};
      #pragma unroll
      for (int i=0;i<4;++i)
        #pragma unroll
        for (int j=0;j<4;++j) acc[i][j] = fmaf(a4[i], b4[j], acc[i][j]);
    }
    __syncthreads();
  }
  // epilogue: h tile -> LDS (overlay), then z = h@W2+b2
  float4 bias = ((const float4*)b1)[tx];
  float bias4[4] = {bias.x, bias.y, bias.z, bias.w};
  float (*hs)[BM+4] = (float(*)[BM+4])smem;
  #pragma unroll
  for (int i=0;i<4;++i){
    #pragma unroll
    for (int j=0;j<4;++j)
      hs[(ty<<2)+i][(tx<<2)+j] = fmaxf(acc[i][j] + bias4[j], 0.0f);
  }
  __syncthreads();
  int row = tid >> 2, lg = tid & 3;
  float4 zacc = ((const float4*)b2s)[lg];
  #pragma unroll 8
  for (int k = 0; k < DH; ++k){
    float hv = hs[row][k];
    float4 wv = *(const float4*)&W2s[k][lg<<2];
    zacc.x = fmaf(hv, wv.x, zacc.x);
    zacc.y = fmaf(hv, wv.y, zacc.y);
    zacc.z = fmaf(hv, wv.z, zacc.z);
    zacc.w = fmaf(hv, wv.w, zacc.w);
  }
  int grow = row0 + row;
  if (grow < N) ((float4*)z)[(size_t)grow*4 + lg] = zacc;
}

// -------- radial flows: one thread per (node, class) --------
__global__ __launch_bounds__(256) void k_flow2(const float* __restrict__ z,
    const float* __restrict__ pc, const float* __restrict__ z0g,
    const float* __restrict__ apg, const float* __restrict__ fbg,
    const float* __restrict__ dinv,
    float* __restrict__ x0, float* __restrict__ c0, float* __restrict__ y0, int N)
{
  __shared__ float z0s[NF][NC][DL];
  __shared__ float alps[NF][NC];
  __shared__ float bhs[NF][NC];
  __shared__ float lpc[NC];
  int tid = threadIdx.x;
  for (int i = tid; i < NF*NC*DL; i += 256)
    z0s[(i>>4)/NC][(i>>4)%NC][i&15] = z0g[i];
  if (tid < NF*NC){
    int l = tid/NC, c = tid%NC;
    float al = softplus_(apg[tid]);
    alps[l][c] = al;
    bhs[l][c]  = -al + softplus_(fbg[tid]);
  }
  if (tid < NC) lpc[tid] = __logf(pc[tid]);
  __syncthreads();

  int idx = blockIdx.x*256 + tid;
  int n = idx >> 4, c = idx & 15;
  if (n >= N) return;
  float dn = dinv[n];
  if (c >= NC){ x0[idx] = 0.f; c0[idx] = 0.f; y0[idx] = 0.f; return; }

  float zz[DL];
  const float4* z4 = (const float4*)z;
  #pragma unroll
  for (int q=0; q<4; ++q){
    float4 v = z4[(size_t)n*4 + q];
    zz[q*4+0]=v.x; zz[q*4+1]=v.y; zz[q*4+2]=v.z; zz[q*4+3]=v.w;
  }
  const float NEGHALFD_LOG2PI = -14.703016531274762f;  // -8*log(2*pi)
  const float LOGSCALE        =  20.248193975754326f;  //  8*log(4*pi)
  float sld = 0.f;
  #pragma unroll 1
  for (int l=0; l<NF; ++l){
    float al = alps[l][c], bhat = bhs[l][c];
    float dz[DL]; float r2 = 0.f;
    #pragma unroll
    for (int d=0; d<DL; ++d){ float t = zz[d] - z0s[l][c][d]; dz[d]=t; r2 = fmaf(t,t,r2); }
    float r  = sqrtf(r2);
    float hh = 1.0f/(al + r);
    float bh = bhat*hh;
    #pragma unroll
    for (int d=0; d<DL; ++d) zz[d] = fmaf(bh, dz[d], zz[d]);
    sld += 15.0f*__logf(1.0f + bh) + __logf(1.0f + bh - bhat*r*hh*hh);
  }
  float q2 = 0.f;
  #pragma unroll
  for (int d=0; d<DL; ++d) q2 = fmaf(zz[d], zz[d], q2);
  float v = -0.5f*q2 + NEGHALFD_LOG2PI + sld + lpc[c] + LOGSCALE;
  v = fminf(fmaxf(v, -30.f), 30.f);
  float xv = __expf(v);
  x0[idx] = xv;
  c0[idx] = dn*xv;
  y0[idx] = 0.1f*dn*xv;
}

// ---------------- bucketed CSR construction ----------------
__global__ __launch_bounds__(256) void k_bhist(const int* __restrict__ dst,
    int* __restrict__ bCnt, int E, int B)
{
  __shared__ int hh[MAXB];
  int tid = threadIdx.x;
  for (int b = tid; b < B; b += 256) hh[b] = 0;
  __syncthreads();
  for (int i = blockIdx.x*256 + tid; i < E; i += gridDim.x*256)
    atomicAdd(&hh[dst[i] >> BSH], 1);
  __syncthreads();
  for (int b = tid; b < B; b += 256) if (hh[b]) atomicAdd(&bCnt[b], hh[b]);
}

// one-block exclusive scan for n <= 1024 (handles in==out); optional total at out[n]
__global__ __launch_bounds__(256) void k_scan_small(const int* __restrict__ in,
    int* __restrict__ out, int n, int writeTotal)
{
  __shared__ int sd[1024];
  int tid = threadIdx.x;
  int orig[4];
  #pragma unroll
  for (int j = 0; j < 4; ++j){
    int i = tid + j*256;
    orig[j] = (i < n) ? in[i] : 0;
    sd[i] = orig[j];
  }
  __syncthreads();
  for (int ofs = 1; ofs < 1024; ofs <<= 1){
    int vals[4];
    #pragma unroll
    for (int j = 0; j < 4; ++j){
      int i = tid + j*256;
      vals[j] = (i >= ofs) ? sd[i-ofs] : 0;
    }
    __syncthreads();
    #pragma unroll
    for (int j = 0; j < 4; ++j) sd[tid + j*256] += vals[j];
    __syncthreads();
  }
  #pragma unroll
  for (int j = 0; j < 4; ++j){
    int i = tid + j*256;
    if (i < n) out[i] = sd[i] - orig[j];    // exclusive
  }
  if (writeTotal && tid == 0) out[n] = sd[n-1];
}

__global__ __launch_bounds__(256) void k_bscatter(const int* __restrict__ src,
    const int* __restrict__ dst, const int* __restrict__ bOff,
    int* __restrict__ bCur, int* __restrict__ bp, int E, int B)
{
  __shared__ int hc[MAXB];
  __shared__ int hb[MAXB];
  int tid = threadIdx.x;
  int base = blockIdx.x * TILE;
  int lim  = base + TILE; if (lim > E) lim = E;
  for (int b = tid; b < B; b += 256) hc[b] = 0;
  __syncthreads();
  for (int i = base + tid; i < lim; i += 256)
    atomicAdd(&hc[dst[i] >> BSH], 1);
  __syncthreads();
  for (int b = tid; b < B; b += 256){
    int c = hc[b];
    hb[b] = c ? atomicAdd(&bCur[b], c) : 0;
    hc[b] = 0;
  }
  __syncthreads();
  for (int i = base + tid; i < lim; i += 256){
    int d = dst[i];
    int b = d >> BSH;
    int pos = bOff[b] + hb[b] + atomicAdd(&hc[b], 1);
    bp[pos] = (src[i] << BSH) | (d & (BW-1));
  }
}

// per-bucket in-degree count (+1 self loop) fused with dinv/dinv2
__global__ __launch_bounds__(256) void k_bdeg(const int* __restrict__ bp,
    const int* __restrict__ bOff, int* __restrict__ deg,
    float* __restrict__ dinv, float* __restrict__ dinv2, int N)
{
  __shared__ int cur[BW];
  int tid = threadIdx.x;
  int b = blockIdx.x;
  if (tid < BW) cur[tid] = 0;
  __syncthreads();
  int s = bOff[b], e = bOff[b+1];
  for (int i = s + tid; i < e; i += 256)
    atomicAdd(&cur[bp[i] & (BW-1)], 1);
  __syncthreads();
  int node = (b << BSH) + tid;
  if (tid < BW && node < N){
    int d = cur[tid] + 1;                 // +1 self loop
    deg[node] = d;
    float dv = 1.0f / sqrtf((float)d);
    dinv[node]  = dv;
    dinv2[node] = dv*dv;
  }
}

__global__ __launch_bounds__(256) void k_scan_part(const int* __restrict__ deg,
    int* __restrict__ part, int N){
  __shared__ int sd[256];
  int base = blockIdx.x*1024;
  int tid = threadIdx.x;
  int s = 0;
  #pragma unroll
  for (int i=0;i<4;++i){ int idx = base + tid*4 + i; if (idx < N) s += deg[idx]; }
  sd[tid] = s; __syncthreads();
  for (int ofs=128; ofs>0; ofs>>=1){ if (tid<ofs) sd[tid]+=sd[tid+ofs]; __syncthreads(); }
  if (tid==0) part[blockIdx.x] = sd[0];
}

__global__ __launch_bounds__(256) void k_scan_final(const int* __restrict__ deg,
    const int* __restrict__ part, int* __restrict__ off, int N, int E)
{
  __shared__ int sc[256];
  int base = blockIdx.x*1024;
  int tid = threadIdx.x;
  int v[4]; int s = 0;
  #pragma unroll
  for (int i=0;i<4;++i){ int idx = base + tid*4 + i; v[i] = (idx<N)?deg[idx]:0; s += v[i]; }
  sc[tid] = s; __syncthreads();
  for (int ofs=1; ofs<256; ofs<<=1){
    int t = (tid>=ofs) ? sc[tid-ofs] : 0;
    __syncthreads();
    sc[tid] += t;
    __syncthreads();
  }
  int ex = sc[tid] - s + part[blockIdx.x];
  #pragma unroll
  for (int i=0;i<4;++i){
    int idx = base + tid*4 + i;
    if (idx < N){
      off[idx] = ex;
      if (idx == N-1) off[N] = ex + v[i];
      ex += v[i];
    }
  }
}

// place self edge (slot 0) + src ints at CSR positions
__global__ __launch_bounds__(256) void k_place(const int* __restrict__ bp,
    const int* __restrict__ bOff, const int* __restrict__ off,
    int* __restrict__ csr, int N)
{
  __shared__ int cur[BW];
  int tid = threadIdx.x;
  int b = blockIdx.x;
  int node0 = b << BSH;
  if (tid < BW){
    cur[tid] = 1;                                 // slot 0 reserved for self
    int node = node0 + tid;
    if (node < N) csr[off[node]] = node;
  }
  __syncthreads();
  int s = bOff[b], e = bOff[b+1];
  for (int i = s + tid; i < e; i += 256){
    int v  = bp[i];
    int dl = v & (BW-1);
    int sn = v >> BSH;
    int d  = node0 + dl;
    int p  = off[d] + atomicAdd(&cur[dl], 1);
    csr[p] = sn;
  }
}

// ---- canonicalize segment order (stable value-rank via shuffles) ----
__global__ __launch_bounds__(256) void k_rank(int* __restrict__ csr,
    const int* __restrict__ off, int N)
{
  int wid  = (blockIdx.x*256 + threadIdx.x) >> 6;
  int lane = threadIdx.x & 63;
  if (wid >= N) return;
  int s = off[wid], e = off[wid+1];
  int d = e - s;
  if (d <= 1) return;
  if (d <= 64){
    int v = (lane < d) ? csr[s+lane] : INT_MAX;
    int rank = 0;
    for (int j = 0; j < d; ++j){
      int bv = __shfl(v, j);
      rank += (bv < v) || (bv == v && j < lane);
    }
    if (lane < d) csr[s+rank] = v;
  } else if (d <= 256){
    int v0 = (lane      < d) ? csr[s+lane      ] : INT_MAX;
    int v1 = (lane+64   < d) ? csr[s+lane+64   ] : INT_MAX;
    int v2 = (lane+128  < d) ? csr[s+lane+128  ] : INT_MAX;
    int v3 = (lane+192  < d) ? csr[s+lane+192  ] : INT_MAX;
    int r0=0,r1=0,r2=0,r3=0;
    for (int j = 0; j < d; ++j){
      int slot = j >> 6, jl = j & 63;
      int bv = (slot==0) ? __shfl(v0,jl) : (slot==1) ? __shfl(v1,jl)
             : (slot==2) ? __shfl(v2,jl) : __shfl(v3,jl);
      r0 += (bv < v0) || (bv == v0 && j < lane);
      r1 += (bv < v1) || (bv == v1 && j < lane+64);
      r2 += (bv < v2) || (bv == v2 && j < lane+128);
      r3 += (bv < v3) || (bv == v3 && j < lane+192);
    }
    if (lane      < d) csr[s+r0]=v0;
    if (lane+64   < d) csr[s+r1]=v1;
    if (lane+128  < d) csr[s+r2]=v2;
    if (lane+192  < d) csr[s+r3]=v3;
  } else {
    if (lane == 0){
      for (int i = s+1; i < e; ++i){
        int key = csr[i]; int j = i-1;
        while (j >= s && csr[j] > key){ csr[j+1] = csr[j]; --j; }
        csr[j+1] = key;
      }
    }
  }
}

// ---- APPNP c-space iteration: 12 threads/node (3 quads x 4 edge-quarters) ----
// Rows stay [N][16] (64B-aligned, no line straddle) but only quads 0-2 carry
// classes 0-11 (10 real + 2 zero-pad) -> 3 lane-requests/edge instead of 4.
// Deterministic: sorted csr, fixed quarter bounds, fixed combine order.
__global__ __launch_bounds__(256) void k_prop(const float* __restrict__ cin,
    const float* __restrict__ y0, const float* __restrict__ dinv2,
    float* __restrict__ cout,
    const int* __restrict__ csr, const int* __restrict__ off, int N)
{
  int t = blockIdx.x*256 + threadIdx.x;
  int n = t / 12, sub = t - n*12;
  int q = sub >> 2, part = sub & 3;        // q in {0,1,2}, part in {0..3}
  if (n >= N) return;
  const float4* c4 = (const float4*)cin;
  int s = off[n], e = off[n+1], d = e - s;
  int lo = s + ((d*part) >> 2);
  int hi = s + ((d*(part+1)) >> 2);
  float4 a0 = make_float4(0.f,0.f,0.f,0.f);
  float4 a1 = make_float4(0.f,0.f,0.f,0.f);
  int i = lo;
  for (; i+4 <= hi; i += 4){
    int s0=csr[i], s1=csr[i+1], s2=csr[i+2], s3=csr[i+3];
    float4 v0 = c4[(size_t)s0*4 + q];
    float4 v1 = c4[(size_t)s1*4 + q];
    float4 v2 = c4[(size_t)s2*4 + q];
    float4 v3 = c4[(size_t)s3*4 + q];
    a0.x+=v0.x; a0.y+=v0.y; a0.z+=v0.z; a0.w+=v0.w;
    a1.x+=v1.x; a1.y+=v1.y; a1.z+=v1.z; a1.w+=v1.w;
    a0.x+=v2.x; a0.y+=v2.y; a0.z+=v2.z; a0.w+=v2.w;
    a1.x+=v3.x; a1.y+=v3.y; a1.z+=v3.z; a1.w+=v3.w;
  }
  for (; i < hi; ++i){
    float4 v = c4[(size_t)csr[i]*4 + q];
    a0.x+=v.x; a0.y+=v.y; a0.z+=v.z; a0.w+=v.w;
  }
  // combine the 4 edge-quarters: lanes 12n+4q .. 12n+4q+3 (4-aligned group)
  float ax = a0.x+a1.x, ay = a0.y+a1.y, az = a0.z+a1.z, aw = a0.w+a1.w;
  ax += __shfl_xor(ax, 1, 4);  ay += __shfl_xor(ay, 1, 4);
  az += __shfl_xor(az, 1, 4);  aw += __shfl_xor(aw, 1, 4);
  ax += __shfl_xor(ax, 2, 4);  ay += __shfl_xor(ay, 2, 4);
  az += __shfl_xor(az, 2, 4);  aw += __shfl_xor(aw, 2, 4);
  if (part == 0){
    float w9 = 0.9f * dinv2[n];
    float4 yv = ((const float4*)y0)[(size_t)n*4 + q];
    float4 o;
    o.x = fmaf(w9, ax, yv.x);
    o.y = fmaf(w9, ay, yv.y);
    o.z = fmaf(w9, az, yv.z);
    o.w = fmaf(w9, aw, yv.w);
    ((float4*)cout)[(size_t)n*4 + q] = o;
  }
}

// ---- last iteration fused with alpha/soft/argmax (16 threads/node; q==3 idle) ----
__global__ __launch_bounds__(256) void k_prop_final(const float* __restrict__ cin,
    const float* __restrict__ x0, const float* __restrict__ dinv,
    const int* __restrict__ csr, const int* __restrict__ off,
    float* __restrict__ out, int N)
{
  int t = blockIdx.x*256 + threadIdx.x;
  int n = t >> 4, sub = t & 15, q = sub & 3, part = sub >> 2;
  if (n >= N) return;
  const float4* c4 = (const float4*)cin;
  int s = off[n], e = off[n+1], d = e - s;
  int lo = s + ((d*part) >> 2);
  int hi = s + ((d*(part+1)) >> 2);
  float4 a0 = make_float4(0.f,0.f,0.f,0.f);
  float4 a1 = make_float4(0.f,0.f,0.f,0.f);
  if (q < 3){
    int i = lo;
    for (; i+4 <= hi; i += 4){
      int s0=csr[i], s1=csr[i+1], s2=csr[i+2], s3=csr[i+3];
      float4 v0 = c4[(size_t)s0*4 + q];
      float4 v1 = c4[(size_t)s1*4 + q];
      float4 v2 = c4[(size_t)s2*4 + q];
      float4 v3 = c4[(size_t)s3*4 + q];
      a0.x+=v0.x; a0.y+=v0.y; a0.z+=v0.z; a0.w+=v0.w;
      a1.x+=v1.x; a1.y+=v1.y; a1.z+=v1.z; a1.w+=v1.w;
      a0.x+=v2.x; a0.y+=v2.y; a0.z+=v2.z; a0.w+=v2.w;
      a1.x+=v3.x; a1.y+=v3.y; a1.z+=v3.z; a1.w+=v3.w;
    }
    for (; i < hi; ++i){
      float4 v = c4[(size_t)csr[i]*4 + q];
      a0.x+=v.x; a0.y+=v.y; a0.z+=v.z; a0.w+=v.w;
    }
  }
  float ax = a0.x+a1.x, ay = a0.y+a1.y, az = a0.z+a1.z, aw = a0.w+a1.w;
  ax += __shfl_xor(ax, 4, 16);  ay += __shfl_xor(ay, 4, 16);
  az += __shfl_xor(az, 4, 16);  aw += __shfl_xor(aw, 4, 16);
  ax += __shfl_xor(ax, 8, 16);  ay += __shfl_xor(ay, 8, 16);
  az += __shfl_xor(az, 8, 16);  aw += __shfl_xor(aw, 8, 16);
  if (part != 0) return;

  float w9 = 0.9f * dinv[n];
  float4 xv = ((const float4*)x0)[(size_t)n*4 + q];
  float4 al;
  al.x = fmaf(w9, ax, fmaf(0.1f, xv.x, 1.f));
  al.y = fmaf(w9, ay, fmaf(0.1f, xv.y, 1.f));
  al.z = fmaf(w9, az, fmaf(0.1f, xv.z, 1.f));
  al.w = fmaf(w9, aw, fmaf(0.1f, xv.w, 1.f));

  float sv = 0.f;
  if (q < 2)       sv = al.x + al.y + al.z + al.w;
  else if (q == 2) sv = al.x + al.y;
  sv += __shfl_xor(sv, 1, 4);
  sv += __shfl_xor(sv, 2, 4);

  float bv = -1e30f; int bi = 999;
  int cb = q*4;
  int nvalid = (q < 2) ? 4 : (q == 2 ? 2 : 0);
  float av[4] = {al.x, al.y, al.z, al.w};
  for (int j = 0; j < nvalid; ++j){
    if (av[j] > bv){ bv = av[j]; bi = cb + j; }
  }
  #pragma unroll
  for (int o = 1; o <= 2; o <<= 1){
    float vo = __shfl_xor(bv, o, 4);
    int  io  = __shfl_xor(bi, o, 4);
    if (vo > bv || (vo == bv && io < bi)){ bv = vo; bi = io; }
  }

  float inv = 1.0f / sv;
  size_t sb = (size_t)N + (size_t)n*NC;
  for (int j = 0; j < nvalid; ++j) out[sb + cb + j] = av[j] * inv;
  if (q == 0) out[n] = (float)bi;
}

extern "C" void kernel_launch(void* const* d_in, const int* in_sizes, int n_in,
                              void* d_out, int out_size, void* d_ws, size_t ws_size,
                              hipStream_t stream)
{
  const float* x  = (const float*)d_in[0];
  const int*   ei = (const int*)  d_in[1];
  const float* pc = (const float*)d_in[2];
  const float* W1 = (const float*)d_in[3];
  const float* b1 = (const float*)d_in[4];
  const float* W2 = (const float*)d_in[5];
  const float* b2 = (const float*)d_in[6];
  const float* z0 = (const float*)d_in[7];
  const float* ap = (const float*)d_in[8];
  const float* fb = (const float*)d_in[9];
  float* out = (float*)d_out;

  const int N = in_sizes[0] / DF;
  const int E = in_sizes[1] / 2;
  const int* src = ei;
  const int* dst = ei + E;
  const int B = (N + BW - 1) >> BSH;

  // Workspace. region0 holds bp (E ints) during CSR build, then z (N*16 f32).
  char* ws = (char*)d_ws;
  size_t o = 0;
  size_t region0 = (size_t)E*sizeof(int);
  if ((size_t)N*DL*sizeof(float) > region0) region0 = (size_t)N*DL*sizeof(float);
  int*   bp   = (int*)  (ws + o);
  float* z    = (float*)(ws + o);
  o += region0;
  int*   csr  = (int*)  (ws + o); o += (size_t)(E+N)*sizeof(int);   // +N self edges
  float* x0   = (float*)(ws + o); o += (size_t)N*DL*sizeof(float);
  float* c0   = (float*)(ws + o); o += (size_t)N*DL*sizeof(float);
  float* y0   = (float*)(ws + o); o += (size_t)N*DL*sizeof(float);
  float* cA   = (float*)(ws + o); o += (size_t)N*DL*sizeof(float);
  float* cB   = (float*)(ws + o); o += (size_t)N*DL*sizeof(float);
  int*   deg  = (int*)  (ws + o); o += (size_t)N*sizeof(int);
  float* dinv = (float*)(ws + o); o += (size_t)N*sizeof(float);
  float* dinv2= (float*)(ws + o); o += (size_t)N*sizeof(float);
  int*   offs = (int*)  (ws + o); o += (size_t)(N+2)*sizeof(int);
  int*   part = (int*)  (ws + o); o += 4096;
  int*   bCnt = (int*)  (ws + o); o += MAXB*sizeof(int);
  int*   bOff = (int*)  (ws + o); o += (MAXB+1)*sizeof(int);
  int*   bCur = (int*)  (ws + o); o += MAXB*sizeof(int);

  const int TB = 256;
  int nb  = (N + 1023) / 1024;

  // Phase 1: bucketed CSR build (bp lives in region0)
  hipMemsetAsync(bCnt, 0, MAXB*sizeof(int), stream);
  hipMemsetAsync(bCur, 0, MAXB*sizeof(int), stream);
  k_bhist<<<512, TB, 0, stream>>>(dst, bCnt, E, B);
  k_scan_small<<<1, TB, 0, stream>>>(bCnt, bOff, B, 1);
  k_bscatter<<<(E + TILE - 1)/TILE, TB, 0, stream>>>(src, dst, bOff, bCur, bp, E, B);
  k_bdeg<<<B, TB, 0, stream>>>(bp, bOff, deg, dinv, dinv2, N);
  k_scan_part<<<nb, TB, 0, stream>>>(deg, part, N);
  k_scan_small<<<1, TB, 0, stream>>>(part, part, nb, 0);
  k_scan_final<<<nb, TB, 0, stream>>>(deg, part, offs, N, E);
  k_place<<<B, TB, 0, stream>>>(bp, bOff, offs, csr, N);
  k_rank<<<(N + 3) / 4, TB, 0, stream>>>(csr, offs, N);

  // Phase 2: encoder fused with z projection (z overwrites bp), then flows
  k_gemm1z<<<(N + BM - 1) / BM, TB, 0, stream>>>(x, W1, b1, W2, b2, z, N);
  k_flow2<<<((N*DL) + TB - 1) / TB, TB, 0, stream>>>(z, pc, z0, ap, fb, dinv,
                                                     x0, c0, y0, N);

  // Phase 3: APPNP in c-space — 9 iterations (12 thr/node) + 1 fused (16 thr/node)
  int gP = ((N*12) + TB - 1) / TB;
  const float* cin = c0;
  for (int it = 0; it < KPROP-1; ++it){
    float* cout = (it & 1) ? cB : cA;
    k_prop<<<gP, TB, 0, stream>>>(cin, y0, dinv2, cout, csr, offs, N);
    cin = cout;
  }
  int gF = ((N*16) + TB - 1) / TB;
  k_prop_final<<<gF, TB, 0, stream>>>(cin, x0, dinv, csr, offs, out, N);
}

// Round 14
// 647.187 us; speedup vs baseline: 1.4221x; 1.1462x over previous
//
#include <hip/hip_runtime.h>
#include <math.h>
#include <limits.h>

#define DF 512
#define DH 64
#define DL 16
#define NC 10
#define NF 10
#define KPROP 10

#define BSH 7                  // bucket shift: 128 nodes per bucket
#define BW  (1 << BSH)
#define MAXB 1024
#define TILE 16384

__device__ __forceinline__ float softplus_(float x){
  return fmaxf(x, 0.0f) + log1pf(expf(-fabsf(x)));
}

__device__ __forceinline__ unsigned int f2bf_(float f){
  unsigned int u = __float_as_uint(f);
  return (u + 0x7FFFu + ((u >> 16) & 1u)) >> 16;          // RNE
}
__device__ __forceinline__ unsigned int pack2bf_(float lo, float hi){
  return f2bf_(lo) | (f2bf_(hi) << 16);
}

// -------- GEMM1 fused with z-projection: z = relu(x@W1+b1) @ W2 + b2 --------
// (proven config: 64x64 tile, 4x4 microtile, BK=32, 124us, 36 VGPR — FINAL)
#define BM 64
#define BN 64
#define BK 32
__global__ __launch_bounds__(256) void k_gemm1z(const float* __restrict__ x,
    const float* __restrict__ W1, const float* __restrict__ b1,
    const float* __restrict__ W2, const float* __restrict__ b2,
    float* __restrict__ z, int N)
{
  __shared__ float smem[2*BK*(BM+4)];           // At | Bs, later overlaid by hs[64][68]
  float (*At)[BM+4] = (float(*)[BM+4])smem;
  float (*Bs)[BN+4] = (float(*)[BN+4])(smem + BK*(BM+4));
  __shared__ float W2s[DH][DL];
  __shared__ float b2s[DL];
  const int tid = threadIdx.x;
  for (int i = tid; i < DH*DL; i += 256) W2s[i>>4][i&15] = W2[i];
  if (tid < DL) b2s[tid] = b2[tid];
  const int tx = tid & 15, ty = tid >> 4;
  const int row0 = blockIdx.x * BM;
  float acc[4][4] = {};
  for (int k0 = 0; k0 < DF; k0 += BK) {
    #pragma unroll
    for (int i = 0; i < 2; ++i) {
      int idx = tid + i*256;
      int r  = idx >> 3;
      int kk = (idx & 7) << 2;
      int row = row0 + r;
      float4 va = make_float4(0.f,0.f,0.f,0.f);
      if (row < N) va = *(const float4*)&x[(size_t)row*DF + k0 + kk];
      At[kk+0][r]=va.x; At[kk+1][r]=va.y; At[kk+2][r]=va.z; At[kk+3][r]=va.w;
      int r2 = idx >> 4;
      int c4 = (idx & 15) << 2;
      float4 vb = *(const float4*)&W1[(size_t)(k0+r2)*DH + c4];
      Bs[r2][c4+0]=vb.x; Bs[r2][c4+1]=vb.y; Bs[r2][c4+2]=vb.z; Bs[r2][c4+3]=vb.w;
    }
    __syncthreads();
    #pragma unroll
    for (int kk = 0; kk < BK; ++kk) {
      float4 av = *(const float4*)&At[kk][ty<<2];
      float4 bv = *(const float4*)&Bs[kk][tx<<2];
      float a4[4]={av.x,av.y,av.z,av.w};
      float b4[4]={bv.x,bv.y,bv.z,bv.w};
      #pragma unroll
      for (int i=0;i<4;++i)
        #pragma unroll
        for (int j=0;j<4;++j) acc[i][j] = fmaf(a4[i], b4[j], acc[i][j]);
    }
    __syncthreads();
  }
  // epilogue: h tile -> LDS (overlay), then z = h@W2+b2
  float4 bias = ((const float4*)b1)[tx];
  float bias4[4] = {bias.x, bias.y, bias.z, bias.w};
  float (*hs)[BM+4] = (float(*)[BM+4])smem;
  #pragma unroll
  for (int i=0;i<4;++i){
    #pragma unroll
    for (int j=0;j<4;++j)
      hs[(ty<<2)+i][(tx<<2)+j] = fmaxf(acc[i][j] + bias4[j], 0.0f);
  }
  __syncthreads();
  int row = tid >> 2, lg = tid & 3;
  float4 zacc = ((const float4*)b2s)[lg];
  #pragma unroll 8
  for (int k = 0; k < DH; ++k){
    float hv = hs[row][k];
    float4 wv = *(const float4*)&W2s[k][lg<<2];
    zacc.x = fmaf(hv, wv.x, zacc.x);
    zacc.y = fmaf(hv, wv.y, zacc.y);
    zacc.z = fmaf(hv, wv.z, zacc.z);
    zacc.w = fmaf(hv, wv.w, zacc.w);
  }
  int grow = row0 + row;
  if (grow < N) ((float4*)z)[(size_t)grow*4 + lg] = zacc;
}

// -------- radial flows: one thread per (node, class) --------
// emits x0 (fp32), y0 = 0.1*dinv*x0 (fp32), c0 = dinv*x0 (bf16)
__global__ __launch_bounds__(256) void k_flow2(const float* __restrict__ z,
    const float* __restrict__ pc, const float* __restrict__ z0g,
    const float* __restrict__ apg, const float* __restrict__ fbg,
    const float* __restrict__ dinv,
    float* __restrict__ x0, unsigned short* __restrict__ c0b,
    float* __restrict__ y0, int N)
{
  __shared__ float z0s[NF][NC][DL];
  __shared__ float alps[NF][NC];
  __shared__ float bhs[NF][NC];
  __shared__ float lpc[NC];
  int tid = threadIdx.x;
  for (int i = tid; i < NF*NC*DL; i += 256)
    z0s[(i>>4)/NC][(i>>4)%NC][i&15] = z0g[i];
  if (tid < NF*NC){
    int l = tid/NC, c = tid%NC;
    float al = softplus_(apg[tid]);
    alps[l][c] = al;
    bhs[l][c]  = -al + softplus_(fbg[tid]);
  }
  if (tid < NC) lpc[tid] = __logf(pc[tid]);
  __syncthreads();

  int idx = blockIdx.x*256 + tid;
  int n = idx >> 4, c = idx & 15;
  if (n >= N) return;
  float dn = dinv[n];
  if (c >= NC){ x0[idx] = 0.f; c0b[idx] = 0; y0[idx] = 0.f; return; }

  float zz[DL];
  const float4* z4 = (const float4*)z;
  #pragma unroll
  for (int q=0; q<4; ++q){
    float4 v = z4[(size_t)n*4 + q];
    zz[q*4+0]=v.x; zz[q*4+1]=v.y; zz[q*4+2]=v.z; zz[q*4+3]=v.w;
  }
  const float NEGHALFD_LOG2PI = -14.703016531274762f;  // -8*log(2*pi)
  const float LOGSCALE        =  20.248193975754326f;  //  8*log(4*pi)
  float sld = 0.f;
  #pragma unroll 1
  for (int l=0; l<NF; ++l){
    float al = alps[l][c], bhat = bhs[l][c];
    float dz[DL]; float r2 = 0.f;
    #pragma unroll
    for (int d=0; d<DL; ++d){ float t = zz[d] - z0s[l][c][d]; dz[d]=t; r2 = fmaf(t,t,r2); }
    float r  = sqrtf(r2);
    float hh = 1.0f/(al + r);
    float bh = bhat*hh;
    #pragma unroll
    for (int d=0; d<DL; ++d) zz[d] = fmaf(bh, dz[d], zz[d]);
    sld += 15.0f*__logf(1.0f + bh) + __logf(1.0f + bh - bhat*r*hh*hh);
  }
  float q2 = 0.f;
  #pragma unroll
  for (int d=0; d<DL; ++d) q2 = fmaf(zz[d], zz[d], q2);
  float v = -0.5f*q2 + NEGHALFD_LOG2PI + sld + lpc[c] + LOGSCALE;
  v = fminf(fmaxf(v, -30.f), 30.f);
  float xv = __expf(v);
  x0[idx] = xv;
  float cv = dn*xv;
  c0b[idx] = (unsigned short)f2bf_(cv);
  y0[idx]  = 0.1f*cv;
}

// ---------------- bucketed CSR construction ----------------
__global__ __launch_bounds__(256) void k_bhist(const int* __restrict__ dst,
    int* __restrict__ bCnt, int E, int B)
{
  __shared__ int hh[MAXB];
  int tid = threadIdx.x;
  for (int b = tid; b < B; b += 256) hh[b] = 0;
  __syncthreads();
  for (int i = blockIdx.x*256 + tid; i < E; i += gridDim.x*256)
    atomicAdd(&hh[dst[i] >> BSH], 1);
  __syncthreads();
  for (int b = tid; b < B; b += 256) if (hh[b]) atomicAdd(&bCnt[b], hh[b]);
}

// one-block exclusive scan for n <= 1024 (handles in==out); optional total at out[n]
__global__ __launch_bounds__(256) void k_scan_small(const int* __restrict__ in,
    int* __restrict__ out, int n, int writeTotal)
{
  __shared__ int sd[1024];
  int tid = threadIdx.x;
  int orig[4];
  #pragma unroll
  for (int j = 0; j < 4; ++j){
    int i = tid + j*256;
    orig[j] = (i < n) ? in[i] : 0;
    sd[i] = orig[j];
  }
  __syncthreads();
  for (int ofs = 1; ofs < 1024; ofs <<= 1){
    int vals[4];
    #pragma unroll
    for (int j = 0; j < 4; ++j){
      int i = tid + j*256;
      vals[j] = (i >= ofs) ? sd[i-ofs] : 0;
    }
    __syncthreads();
    #pragma unroll
    for (int j = 0; j < 4; ++j) sd[tid + j*256] += vals[j];
    __syncthreads();
  }
  #pragma unroll
  for (int j = 0; j < 4; ++j){
    int i = tid + j*256;
    if (i < n) out[i] = sd[i] - orig[j];    // exclusive
  }
  if (writeTotal && tid == 0) out[n] = sd[n-1];
}

__global__ __launch_bounds__(256) void k_bscatter(const int* __restrict__ src,
    const int* __restrict__ dst, const int* __restrict__ bOff,
    int* __restrict__ bCur, int* __restrict__ bp, int E, int B)
{
  __shared__ int hc[MAXB];
  __shared__ int hb[MAXB];
  int tid = threadIdx.x;
  int base = blockIdx.x * TILE;
  int lim  = base + TILE; if (lim > E) lim = E;
  for (int b = tid; b < B; b += 256) hc[b] = 0;
  __syncthreads();
  for (int i = base + tid; i < lim; i += 256)
    atomicAdd(&hc[dst[i] >> BSH], 1);
  __syncthreads();
  for (int b = tid; b < B; b += 256){
    int c = hc[b];
    hb[b] = c ? atomicAdd(&bCur[b], c) : 0;
    hc[b] = 0;
  }
  __syncthreads();
  for (int i = base + tid; i < lim; i += 256){
    int d = dst[i];
    int b = d >> BSH;
    int pos = bOff[b] + hb[b] + atomicAdd(&hc[b], 1);
    bp[pos] = (src[i] << BSH) | (d & (BW-1));
  }
}

// per-bucket in-degree count (+1 self loop) fused with dinv/dinv2
__global__ __launch_bounds__(256) void k_bdeg(const int* __restrict__ bp,
    const int* __restrict__ bOff, int* __restrict__ deg,
    float* __restrict__ dinv, float* __restrict__ dinv2, int N)
{
  __shared__ int cur[BW];
  int tid = threadIdx.x;
  int b = blockIdx.x;
  if (tid < BW) cur[tid] = 0;
  __syncthreads();
  int s = bOff[b], e = bOff[b+1];
  for (int i = s + tid; i < e; i += 256)
    atomicAdd(&cur[bp[i] & (BW-1)], 1);
  __syncthreads();
  int node = (b << BSH) + tid;
  if (tid < BW && node < N){
    int d = cur[tid] + 1;                 // +1 self loop
    deg[node] = d;
    float dv = 1.0f / sqrtf((float)d);
    dinv[node]  = dv;
    dinv2[node] = dv*dv;
  }
}

__global__ __launch_bounds__(256) void k_scan_part(const int* __restrict__ deg,
    int* __restrict__ part, int N){
  __shared__ int sd[256];
  int base = blockIdx.x*1024;
  int tid = threadIdx.x;
  int s = 0;
  #pragma unroll
  for (int i=0;i<4;++i){ int idx = base + tid*4 + i; if (idx < N) s += deg[idx]; }
  sd[tid] = s; __syncthreads();
  for (int ofs=128; ofs>0; ofs>>=1){ if (tid<ofs) sd[tid]+=sd[tid+ofs]; __syncthreads(); }
  if (tid==0) part[blockIdx.x] = sd[0];
}

__global__ __launch_bounds__(256) void k_scan_final(const int* __restrict__ deg,
    const int* __restrict__ part, int* __restrict__ off, int N, int E)
{
  __shared__ int sc[256];
  int base = blockIdx.x*1024;
  int tid = threadIdx.x;
  int v[4]; int s = 0;
  #pragma unroll
  for (int i=0;i<4;++i){ int idx = base + tid*4 + i; v[i] = (idx<N)?deg[idx]:0; s += v[i]; }
  sc[tid] = s; __syncthreads();
  for (int ofs=1; ofs<256; ofs<<=1){
    int t = (tid>=ofs) ? sc[tid-ofs] : 0;
    __syncthreads();
    sc[tid] += t;
    __syncthreads();
  }
  int ex = sc[tid] - s + part[blockIdx.x];
  #pragma unroll
  for (int i=0;i<4;++i){
    int idx = base + tid*4 + i;
    if (idx < N){
      off[idx] = ex;
      if (idx == N-1) off[N] = ex + v[i];
      ex += v[i];
    }
  }
}

// place self edge (slot 0) + src ints at CSR positions
__global__ __launch_bounds__(256) void k_place(const int* __restrict__ bp,
    const int* __restrict__ bOff, const int* __restrict__ off,
    int* __restrict__ csr, int N)
{
  __shared__ int cur[BW];
  int tid = threadIdx.x;
  int b = blockIdx.x;
  int node0 = b << BSH;
  if (tid < BW){
    cur[tid] = 1;                                 // slot 0 reserved for self
    int node = node0 + tid;
    if (node < N) csr[off[node]] = node;
  }
  __syncthreads();
  int s = bOff[b], e = bOff[b+1];
  for (int i = s + tid; i < e; i += 256){
    int v  = bp[i];
    int dl = v & (BW-1);
    int sn = v >> BSH;
    int d  = node0 + dl;
    int p  = off[d] + atomicAdd(&cur[dl], 1);
    csr[p] = sn;
  }
}

// ---- canonicalize segment order (stable value-rank via shuffles) ----
__global__ __launch_bounds__(256) void k_rank(int* __restrict__ csr,
    const int* __restrict__ off, int N)
{
  int wid  = (blockIdx.x*256 + threadIdx.x) >> 6;
  int lane = threadIdx.x & 63;
  if (wid >= N) return;
  int s = off[wid], e = off[wid+1];
  int d = e - s;
  if (d <= 1) return;
  if (d <= 64){
    int v = (lane < d) ? csr[s+lane] : INT_MAX;
    int rank = 0;
    for (int j = 0; j < d; ++j){
      int bv = __shfl(v, j);
      rank += (bv < v) || (bv == v && j < lane);
    }
    if (lane < d) csr[s+rank] = v;
  } else if (d <= 256){
    int v0 = (lane      < d) ? csr[s+lane      ] : INT_MAX;
    int v1 = (lane+64   < d) ? csr[s+lane+64   ] : INT_MAX;
    int v2 = (lane+128  < d) ? csr[s+lane+128  ] : INT_MAX;
    int v3 = (lane+192  < d) ? csr[s+lane+192  ] : INT_MAX;
    int r0=0,r1=0,r2=0,r3=0;
    for (int j = 0; j < d; ++j){
      int slot = j >> 6, jl = j & 63;
      int bv = (slot==0) ? __shfl(v0,jl) : (slot==1) ? __shfl(v1,jl)
             : (slot==2) ? __shfl(v2,jl) : __shfl(v3,jl);
      r0 += (bv < v0) || (bv == v0 && j < lane);
      r1 += (bv < v1) || (bv == v1 && j < lane+64);
      r2 += (bv < v2) || (bv == v2 && j < lane+128);
      r3 += (bv < v3) || (bv == v3 && j < lane+192);
    }
    if (lane      < d) csr[s+r0]=v0;
    if (lane+64   < d) csr[s+r1]=v1;
    if (lane+128  < d) csr[s+r2]=v2;
    if (lane+192  < d) csr[s+r3]=v3;
  } else {
    if (lane == 0){
      for (int i = s+1; i < e; ++i){
        int key = csr[i]; int j = i-1;
        while (j >= s && csr[j] > key){ csr[j+1] = csr[j]; --j; }
        csr[j+1] = key;
      }
    }
  }
}

// ---- APPNP c-space iteration, bf16 state: 8 threads/node ----
// sub = tid&7: qh = sub>>2 (bf16 half-row: 8 classes = 16B), part = sub&3
// (edge quarter). Row = 16 bf16 = 32B -> 2 lane-requests/edge. fp32 accum.
// Deterministic: sorted csr, fixed quarter bounds, fixed combine order.
__global__ __launch_bounds__(256) void k_prop(const uint4* __restrict__ cin,
    const float* __restrict__ y0, const float* __restrict__ dinv2,
    uint4* __restrict__ cout,
    const int* __restrict__ csr, const int* __restrict__ off, int N)
{
  int t = blockIdx.x*256 + threadIdx.x;
  int n = t >> 3, sub = t & 7, qh = sub >> 2, part = sub & 3;
  if (n >= N) return;
  int s = off[n], e = off[n+1], d = e - s;
  int lo = s + ((d*part) >> 2);
  int hi = s + ((d*(part+1)) >> 2);
  float a[8] = {0.f,0.f,0.f,0.f,0.f,0.f,0.f,0.f};
  float b[8] = {0.f,0.f,0.f,0.f,0.f,0.f,0.f,0.f};
  int i = lo;
  for (; i+2 <= hi; i += 2){
    int s0 = csr[i], s1 = csr[i+1];
    uint4 u0 = cin[(size_t)s0*2 + qh];
    uint4 u1 = cin[(size_t)s1*2 + qh];
    a[0] += __uint_as_float(u0.x << 16); a[1] += __uint_as_float(u0.x & 0xFFFF0000u);
    a[2] += __uint_as_float(u0.y << 16); a[3] += __uint_as_float(u0.y & 0xFFFF0000u);
    a[4] += __uint_as_float(u0.z << 16); a[5] += __uint_as_float(u0.z & 0xFFFF0000u);
    a[6] += __uint_as_float(u0.w << 16); a[7] += __uint_as_float(u0.w & 0xFFFF0000u);
    b[0] += __uint_as_float(u1.x << 16); b[1] += __uint_as_float(u1.x & 0xFFFF0000u);
    b[2] += __uint_as_float(u1.y << 16); b[3] += __uint_as_float(u1.y & 0xFFFF0000u);
    b[4] += __uint_as_float(u1.z << 16); b[5] += __uint_as_float(u1.z & 0xFFFF0000u);
    b[6] += __uint_as_float(u1.w << 16); b[7] += __uint_as_float(u1.w & 0xFFFF0000u);
  }
  if (i < hi){
    uint4 u0 = cin[(size_t)csr[i]*2 + qh];
    a[0] += __uint_as_float(u0.x << 16); a[1] += __uint_as_float(u0.x & 0xFFFF0000u);
    a[2] += __uint_as_float(u0.y << 16); a[3] += __uint_as_float(u0.y & 0xFFFF0000u);
    a[4] += __uint_as_float(u0.z << 16); a[5] += __uint_as_float(u0.z & 0xFFFF0000u);
    a[6] += __uint_as_float(u0.w << 16); a[7] += __uint_as_float(u0.w & 0xFFFF0000u);
  }
  float v[8];
  #pragma unroll
  for (int j = 0; j < 8; ++j){
    float t2 = a[j] + b[j];
    t2 += __shfl_xor(t2, 1, 4);
    t2 += __shfl_xor(t2, 2, 4);
    v[j] = t2;
  }
  if (part == 0){
    float w9 = 0.9f * dinv2[n];
    const float4* y4 = (const float4*)y0;
    float4 ya = y4[(size_t)n*4 + qh*2];
    float4 yb = y4[(size_t)n*4 + qh*2 + 1];
    float o0 = fmaf(w9, v[0], ya.x), o1 = fmaf(w9, v[1], ya.y);
    float o2 = fmaf(w9, v[2], ya.z), o3 = fmaf(w9, v[3], ya.w);
    float o4 = fmaf(w9, v[4], yb.x), o5 = fmaf(w9, v[5], yb.y);
    float o6 = fmaf(w9, v[6], yb.z), o7 = fmaf(w9, v[7], yb.w);
    uint4 w;
    w.x = pack2bf_(o0, o1); w.y = pack2bf_(o2, o3);
    w.z = pack2bf_(o4, o5); w.w = pack2bf_(o6, o7);
    cout[(size_t)n*2 + qh] = w;
  }
}

// ---- last iteration fused with alpha/soft/argmax (8 threads/node) ----
__global__ __launch_bounds__(256) void k_prop_final(const uint4* __restrict__ cin,
    const float* __restrict__ x0, const float* __restrict__ dinv,
    const int* __restrict__ csr, const int* __restrict__ off,
    float* __restrict__ out, int N)
{
  int t = blockIdx.x*256 + threadIdx.x;
  int n = t >> 3, sub = t & 7, qh = sub >> 2, part = sub & 3;
  if (n >= N) return;
  int s = off[n], e = off[n+1], d = e - s;
  int lo = s + ((d*part) >> 2);
  int hi = s + ((d*(part+1)) >> 2);
  float a[8] = {0.f,0.f,0.f,0.f,0.f,0.f,0.f,0.f};
  float b[8] = {0.f,0.f,0.f,0.f,0.f,0.f,0.f,0.f};
  int i = lo;
  for (; i+2 <= hi; i += 2){
    int s0 = csr[i], s1 = csr[i+1];
    uint4 u0 = cin[(size_t)s0*2 + qh];
    uint4 u1 = cin[(size_t)s1*2 + qh];
    a[0] += __uint_as_float(u0.x << 16); a[1] += __uint_as_float(u0.x & 0xFFFF0000u);
    a[2] += __uint_as_float(u0.y << 16); a[3] += __uint_as_float(u0.y & 0xFFFF0000u);
    a[4] += __uint_as_float(u0.z << 16); a[5] += __uint_as_float(u0.z & 0xFFFF0000u);
    a[6] += __uint_as_float(u0.w << 16); a[7] += __uint_as_float(u0.w & 0xFFFF0000u);
    b[0] += __uint_as_float(u1.x << 16); b[1] += __uint_as_float(u1.x & 0xFFFF0000u);
    b[2] += __uint_as_float(u1.y << 16); b[3] += __uint_as_float(u1.y & 0xFFFF0000u);
    b[4] += __uint_as_float(u1.z << 16); b[5] += __uint_as_float(u1.z & 0xFFFF0000u);
    b[6] += __uint_as_float(u1.w << 16); b[7] += __uint_as_float(u1.w & 0xFFFF0000u);
  }
  if (i < hi){
    uint4 u0 = cin[(size_t)csr[i]*2 + qh];
    a[0] += __uint_as_float(u0.x << 16); a[1] += __uint_as_float(u0.x & 0xFFFF0000u);
    a[2] += __uint_as_float(u0.y << 16); a[3] += __uint_as_float(u0.y & 0xFFFF0000u);
    a[4] += __uint_as_float(u0.z << 16); a[5] += __uint_as_float(u0.z & 0xFFFF0000u);
    a[6] += __uint_as_float(u0.w << 16); a[7] += __uint_as_float(u0.w & 0xFFFF0000u);
  }
  float v[8];
  #pragma unroll
  for (int j = 0; j < 8; ++j){
    float t2 = a[j] + b[j];
    t2 += __shfl_xor(t2, 1, 4);
    t2 += __shfl_xor(t2, 2, 4);
    v[j] = t2;
  }
  if (part != 0) return;

  float w9 = 0.9f * dinv[n];
  const float4* x4 = (const float4*)x0;
  float4 xa = x4[(size_t)n*4 + qh*2];
  float4 xb = x4[(size_t)n*4 + qh*2 + 1];
  float xv[8] = {xa.x, xa.y, xa.z, xa.w, xb.x, xb.y, xb.z, xb.w};
  float al[8];
  #pragma unroll
  for (int j = 0; j < 8; ++j) al[j] = fmaf(w9, v[j], fmaf(0.1f, xv[j], 1.f));

  int nv = qh ? 2 : 8;              // qh0: classes 0-7, qh1: classes 8-9
  float sv = 0.f;
  for (int j = 0; j < nv; ++j) sv += al[j];
  sv += __shfl_xor(sv, 4, 8);

  float bv = -1e30f; int bi = 999;
  for (int j = 0; j < nv; ++j){
    if (al[j] > bv){ bv = al[j]; bi = qh*8 + j; }
  }
  {
    float vo = __shfl_xor(bv, 4, 8);
    int  io  = __shfl_xor(bi, 4, 8);
    if (vo > bv || (vo == bv && io < bi)){ bv = vo; bi = io; }
  }

  float inv = 1.0f / sv;
  size_t sb = (size_t)N + (size_t)n*NC;
  for (int j = 0; j < nv; ++j) out[sb + qh*8 + j] = al[j] * inv;
  if (sub == 0) out[n] = (float)bi;
}

extern "C" void kernel_launch(void* const* d_in, const int* in_sizes, int n_in,
                              void* d_out, int out_size, void* d_ws, size_t ws_size,
                              hipStream_t stream)
{
  const float* x  = (const float*)d_in[0];
  const int*   ei = (const int*)  d_in[1];
  const float* pc = (const float*)d_in[2];
  const float* W1 = (const float*)d_in[3];
  const float* b1 = (const float*)d_in[4];
  const float* W2 = (const float*)d_in[5];
  const float* b2 = (const float*)d_in[6];
  const float* z0 = (const float*)d_in[7];
  const float* ap = (const float*)d_in[8];
  const float* fb = (const float*)d_in[9];
  float* out = (float*)d_out;

  const int N = in_sizes[0] / DF;
  const int E = in_sizes[1] / 2;
  const int* src = ei;
  const int* dst = ei + E;
  const int B = (N + BW - 1) >> BSH;

  // Workspace. region0 holds bp (E ints) during CSR build, then z (N*16 f32).
  char* ws = (char*)d_ws;
  size_t o = 0;
  size_t region0 = (size_t)E*sizeof(int);
  if ((size_t)N*DL*sizeof(float) > region0) region0 = (size_t)N*DL*sizeof(float);
  int*   bp   = (int*)  (ws + o);
  float* z    = (float*)(ws + o);
  o += region0;
  int*   csr  = (int*)  (ws + o); o += (size_t)(E+N)*sizeof(int);   // +N self edges
  float* x0   = (float*)(ws + o); o += (size_t)N*DL*sizeof(float);
  float* y0   = (float*)(ws + o); o += (size_t)N*DL*sizeof(float);
  unsigned short* c0b = (unsigned short*)(ws + o); o += (size_t)N*DL*2;
  unsigned short* cAb = (unsigned short*)(ws + o); o += (size_t)N*DL*2;
  unsigned short* cBb = (unsigned short*)(ws + o); o += (size_t)N*DL*2;
  int*   deg  = (int*)  (ws + o); o += (size_t)N*sizeof(int);
  float* dinv = (float*)(ws + o); o += (size_t)N*sizeof(float);
  float* dinv2= (float*)(ws + o); o += (size_t)N*sizeof(float);
  int*   offs = (int*)  (ws + o); o += (size_t)(N+2)*sizeof(int);
  int*   part = (int*)  (ws + o); o += 4096;
  int*   bCnt = (int*)  (ws + o); o += MAXB*sizeof(int);
  int*   bOff = (int*)  (ws + o); o += (MAXB+1)*sizeof(int);
  int*   bCur = (int*)  (ws + o); o += MAXB*sizeof(int);

  const int TB = 256;
  int nb  = (N + 1023) / 1024;

  // Phase 1: bucketed CSR build (bp lives in region0)
  hipMemsetAsync(bCnt, 0, MAXB*sizeof(int), stream);
  hipMemsetAsync(bCur, 0, MAXB*sizeof(int), stream);
  k_bhist<<<512, TB, 0, stream>>>(dst, bCnt, E, B);
  k_scan_small<<<1, TB, 0, stream>>>(bCnt, bOff, B, 1);
  k_bscatter<<<(E + TILE - 1)/TILE, TB, 0, stream>>>(src, dst, bOff, bCur, bp, E, B);
  k_bdeg<<<B, TB, 0, stream>>>(bp, bOff, deg, dinv, dinv2, N);
  k_scan_part<<<nb, TB, 0, stream>>>(deg, part, N);
  k_scan_small<<<1, TB, 0, stream>>>(part, part, nb, 0);
  k_scan_final<<<nb, TB, 0, stream>>>(deg, part, offs, N, E);
  k_place<<<B, TB, 0, stream>>>(bp, bOff, offs, csr, N);
  k_rank<<<(N + 3) / 4, TB, 0, stream>>>(csr, offs, N);

  // Phase 2: encoder fused with z projection (z overwrites bp), then flows
  k_gemm1z<<<(N + BM - 1) / BM, TB, 0, stream>>>(x, W1, b1, W2, b2, z, N);
  k_flow2<<<((N*DL) + TB - 1) / TB, TB, 0, stream>>>(z, pc, z0, ap, fb, dinv,
                                                     x0, c0b, y0, N);

  // Phase 3: APPNP in bf16 c-space — 9 iterations + 1 fused, 8 thr/node
  int gP = ((N*8) + TB - 1) / TB;
  const unsigned short* cin = c0b;
  for (int it = 0; it < KPROP-1; ++it){
    unsigned short* cout = (it & 1) ? cBb : cAb;
    k_prop<<<gP, TB, 0, stream>>>((const uint4*)cin, y0, dinv2,
                                  (uint4*)cout, csr, offs, N);
    cin = cout;
  }
  k_prop_final<<<gP, TB, 0, stream>>>((const uint4*)cin, x0, dinv,
                                      csr, offs, out, N);
}